// Round 6
// baseline (440.832 us; speedup 1.0000x reference)
//
#include <hip/hip_runtime.h>
#include <hip/hip_bf16.h>
#include <hip/hip_cooperative_groups.h>

namespace cg = cooperative_groups;

typedef __attribute__((ext_vector_type(8))) short bf16x8;
typedef __attribute__((ext_vector_type(8))) unsigned short u16x8;
typedef __attribute__((ext_vector_type(4))) float f32x4;

#define LLW 4194304

// ---------------- param bundle ----------------------------------------------
struct FFParams {
  const float* BB1; const int* Pi1; const float* GG1;
  const float* BB2; const int* Pi2; const float* GG2;
  unsigned short* m4b; float* partial; const float* theta;
  const float* BBb1; const int* Pib1; const float* GGb1; const float* ib1;
  float* b1w;
  const float* BBb2; const int* Pib2; const float* GGb2; const float* ib2;
  float* b2w;
  const float* x; __hip_bfloat16* xb;
  const float* iW1; const float* iW2;
  __hip_bfloat16* W1b; __hip_bfloat16* W2b;
  __hip_bfloat16* hb; float* out;
};

// ---------------- in-register FWHT over N entries spaced S apart ------------
template <int N, int S>
__device__ __forceinline__ void reg_fwht(float* v) {
#pragma unroll
  for (int h = 1; h < N; h <<= 1)
#pragma unroll
    for (int g = 0; g < N; g += 2 * h)
#pragma unroll
      for (int j = 0; j < h; ++j) {
        float a = v[(g + j) * S], b = v[(g + j + h) * S];
        v[(g + j) * S] = a + b;
        v[(g + j + h) * S] = a - b;
      }
}

__device__ __forceinline__ unsigned short f2bf(float f) {
  unsigned u = __float_as_uint(f);
  unsigned r = (u + 0x7fff + ((u >> 16) & 1)) >> 16;
  return (unsigned short)r;
}

// generic barriered LDS FWHT (tiny bias2 only)
__device__ __forceinline__ void lds_fwht(float* s, int n, int tid, int T) {
  for (int h = 1; h < n; h <<= 1) {
    __syncthreads();
    for (int t = tid; t < (n >> 1); t += T) {
      int i0 = ((t & ~(h - 1)) << 1) | (t & (h - 1));
      int i1 = i0 + h;
      float a = s[i0], b = s[i1];
      s[i0] = a + b;
      s[i1] = a - b;
    }
  }
  __syncthreads();
}

// ---------------- register FWHT-2048 with 256 threads -----------------------
// pad: 2304 floats scratch; dst: 2048 floats output (must not alias pad)
__device__ __forceinline__ void fwht2048_block(float w[8], float* pad,
                                               float* dst, int t) {
  reg_fwht<8, 1>(w);  // bits 8..10
#pragma unroll
  for (int j = 0; j < 8; ++j) {
    int i = t + 256 * j;
    pad[i + 4 * (i >> 5)] = w[j];
  }
  __syncthreads();
  {  // bits 0..2
    int base = 8 * t + 4 * (t >> 2);
    float4 a = *(float4*)(pad + base);
    float4 b = *(float4*)(pad + base + 4);
    float u[8] = {a.x, a.y, a.z, a.w, b.x, b.y, b.z, b.w};
    reg_fwht<8, 1>(u);
    *(float4*)(pad + base) = make_float4(u[0], u[1], u[2], u[3]);
    *(float4*)(pad + base + 4) = make_float4(u[4], u[5], u[6], u[7]);
  }
  __syncthreads();
  {  // bits 3..5
    int b0 = (t & 7) + 64 * (t >> 3);
    float u[8];
#pragma unroll
    for (int j = 0; j < 8; ++j) {
      int i = b0 + 8 * j;
      u[j] = pad[i + 4 * (i >> 5)];
    }
    reg_fwht<8, 1>(u);
#pragma unroll
    for (int j = 0; j < 8; ++j) {
      int i = b0 + 8 * j;
      pad[i + 4 * (i >> 5)] = u[j];
    }
  }
  __syncthreads();
  // bits 6..7 -> dst unpadded
#pragma unroll
  for (int g = 0; g < 2; ++g) {
    int b0 = (t & 63) + 256 * ((g << 2) | (t >> 6));
    float u[4];
#pragma unroll
    for (int j = 0; j < 4; ++j) {
      int i = b0 + 64 * j;
      u[j] = pad[i + 4 * (i >> 5)];
    }
    reg_fwht<4, 1>(u);
#pragma unroll
    for (int j = 0; j < 4; ++j) dst[b0 + 64 * j] = u[j];
  }
  __syncthreads();
}

// ---------------- front pipe body (one of 1024 chunk-jobs) ------------------
// In-block m2 = fwht2048(BB*theta); then gather+scale, FWHT-8192, bf16 pack
// to m4b TRANSPOSED by 16-col groups. Uses s[0..9211] + red[0..3].
__device__ __forceinline__ void front_pipe(const FFParams& p, int job, int t,
                                           float* s, float* red) {
  int pipe = job >> 9, chunk = job & 511;
  const float* BB = pipe ? p.BB2 : p.BB1;
  const int* Pi = pipe ? p.Pi2 : p.Pi1;
  const float* GG = pipe ? p.GG2 : p.GG1;

  {
    float w8[8];
#pragma unroll
    for (int j = 0; j < 8; ++j) {
      int i = t + 256 * j;
      w8[j] = BB[i] * p.theta[i];
    }
    fwht2048_block(w8, s + 2304, s, t);
  }

  long base = (long)chunk * 8192;
  const int4* p4 = (const int4*)(Pi + base);
  const float4* g4 = (const float4*)(GG + base);
  float v[32];
  float lsum = 0.f;
#pragma unroll
  for (int j = 0; j < 8; ++j) {  // i = t*4 + e + j*1024
    int4 pp = p4[t + j * 256];
    float4 g = g4[t + j * 256];
    lsum += g.x * g.x + g.y * g.y + g.z * g.z + g.w * g.w;
    v[j * 4 + 0] = s[pp.x & 2047] * g.x;
    v[j * 4 + 1] = s[pp.y & 2047] * g.y;
    v[j * 4 + 2] = s[pp.z & 2047] * g.z;
    v[j * 4 + 3] = s[pp.w & 2047] * g.w;
  }
  for (int off = 32; off; off >>= 1) lsum += __shfl_down(lsum, off, 64);
  if ((t & 63) == 0) red[t >> 6] = lsum;

#pragma unroll
  for (int e = 0; e < 4; ++e) reg_fwht<8, 4>(v + e);  // bits 10..12

  __syncthreads();  // tab reads + red writes complete; s reusable
  if (t == 0)
    p.partial[pipe * 512 + chunk] = red[0] + red[1] + red[2] + red[3];

#pragma unroll
  for (int j = 0; j < 8; ++j) {
    int A = t * 4 + 4 * (t >> 3) + j * 1152;
    *(float4*)(s + A) =
        make_float4(v[j * 4], v[j * 4 + 1], v[j * 4 + 2], v[j * 4 + 3]);
  }
  __syncthreads();
  {  // bits 5..9
    int b0 = (t & 31) + (t >> 5) * 1024;
    float w[32];
#pragma unroll
    for (int j2 = 0; j2 < 32; ++j2) {
      int i = b0 + j2 * 32;
      w[j2] = s[i + 4 * (i >> 5)];
    }
    reg_fwht<32, 1>(w);
#pragma unroll
    for (int j2 = 0; j2 < 32; ++j2) {
      int i = b0 + j2 * 32;
      s[i + 4 * (i >> 5)] = w[j2];
    }
  }
  __syncthreads();
  // bits 0..4: thread owns c = t*32..t*32+31 (contiguous)
#pragma unroll
  for (int q = 0; q < 8; ++q) {
    float4 r = *(const float4*)(s + t * 36 + q * 4);
    v[q * 4 + 0] = r.x;
    v[q * 4 + 1] = r.y;
    v[q * 4 + 2] = r.z;
    v[q * 4 + 3] = r.w;
  }
  reg_fwht<32, 1>(v);
  // transposed write: col-groups 2t, 2t+1; 32B per group
  unsigned short* o = p.m4b + (long)pipe * LLW;
  long a0 = (long)(2 * t) * 8192 + (long)chunk * 16;
#pragma unroll
  for (int q = 0; q < 4; ++q) {
    u16x8 pk;
#pragma unroll
    for (int e = 0; e < 8; ++e) pk[e] = f2bf(v[q * 8 + e]);
    *(u16x8*)(o + a0 + (q >> 1) * 8192 + (q & 1) * 8) = pk;
  }
}

// ---------------- bias1: LL=4096, K=2048, DD=3072 (uses s[0..8191]) ---------
__device__ __forceinline__ void bias1_job(const FFParams& p, int t, float* s) {
  float* tabd = s + 6144;
  float w[8];
#pragma unroll
  for (int j = 0; j < 8; ++j) {
    int i = t + 256 * j;
    w[j] = p.BBb1[i] * p.theta[i];
  }
  fwht2048_block(w, s, tabd, t);

  float w16[16];
  float lsum = 0.f;
#pragma unroll
  for (int j = 0; j < 16; ++j) {
    int i = t + 256 * j;
    float g = p.GGb1[i];
    lsum += g * g;
    w16[j] = tabd[p.Pib1[i] & 2047] * g;
  }
  reg_fwht<16, 1>(w16);  // bits 8..11
#pragma unroll
  for (int j = 0; j < 16; ++j) {
    int i = t + 256 * j;
    s[i + 4 * (i >> 5)] = w16[j];
  }
  for (int off = 32; off; off >>= 1) lsum += __shfl_down(lsum, off, 64);
  if ((t & 63) == 0) s[4608 + (t >> 6)] = lsum;
  __syncthreads();
  float S = s[4608] + s[4609] + s[4610] + s[4611];
  {  // bits 0..3
    int base16 = 16 * t + 4 * (t >> 1);
    float u[16];
#pragma unroll
    for (int q = 0; q < 4; ++q) {
      float4 r = *(float4*)(s + base16 + q * 4);
      u[q * 4 + 0] = r.x;
      u[q * 4 + 1] = r.y;
      u[q * 4 + 2] = r.z;
      u[q * 4 + 3] = r.w;
    }
    reg_fwht<16, 1>(u);
#pragma unroll
    for (int q = 0; q < 4; ++q)
      *(float4*)(s + base16 + q * 4) =
          make_float4(u[q * 4], u[q * 4 + 1], u[q * 4 + 2], u[q * 4 + 3]);
  }
  __syncthreads();
  {  // bits 4..7 + epilogue
    float scale = 1.0f / sqrtf(S * 3072.0f);
    int b0 = (t & 15) + 256 * (t >> 4);
    float u[16];
#pragma unroll
    for (int j = 0; j < 16; ++j) {
      int i = b0 + 16 * j;
      u[j] = s[i + 4 * (i >> 5)];
    }
    reg_fwht<16, 1>(u);
#pragma unroll
    for (int j = 0; j < 16; ++j) {
      int i = b0 + 16 * j;
      if (i < 3072) p.b1w[i] = p.ib1[i] + u[j] * scale;
    }
  }
}

// ---------------- bias2: LL=1024, K=1024, DD=768 (uses s[0..2051]) ----------
__device__ __forceinline__ void bias2_job(const FFParams& p, int t, float* s) {
  float* tab2 = s;
  float* m42 = s + 1024;
  for (int i = t; i < 1024; i += 256) tab2[i] = p.BBb2[i] * p.theta[i];
  lds_fwht(tab2, 1024, t, 256);
  float lsum = 0.f;
  for (int i = t; i < 1024; i += 256) {
    float g = p.GGb2[i];
    lsum += g * g;
    m42[i] = tab2[p.Pib2[i] & 1023] * g;
  }
  for (int off = 32; off; off >>= 1) lsum += __shfl_down(lsum, off, 64);
  if ((t & 63) == 0) s[2048 + (t >> 6)] = lsum;
  lds_fwht(m42, 1024, t, 256);
  float S = s[2048] + s[2049] + s[2050] + s[2051];
  float scale = 1.0f / sqrtf(S * 768.0f);
  for (int i = t; i < 768; i += 256) p.b2w[i] = p.ib2[i] + m42[i] * scale;
}

// ---------------- f2c body: FWHT over bits 13..21 + epilogue (one job) ------
// LDS layout: idx(r,c) = r*20 + c (max 10235). red = 4-float scratch at
// s+10236 (disjoint). Verified in round 4 (passed).
__device__ __forceinline__ void f2c_body(
    const unsigned short* __restrict__ mpipe, const float* __restrict__ initW,
    unsigned short* __restrict__ outW, const float* __restrict__ partial_p,
    int lb, int t, float* s, float* red) {
  int g = ((lb & 7) << 6) | (lb >> 3);
  int l0 = g * 16;
  const unsigned short* mp = mpipe + (long)g * 8192;

  // reduce the 512 per-job sum(GG^2) partials (L2-hot) -> red[]
  {
    float ps = partial_p[t] + partial_p[256 + t];
    for (int off = 32; off; off >>= 1) ps += __shfl_down(ps, off, 64);
    if ((t & 63) == 0) red[t >> 6] = ps;
  }

  // contiguous 16KB read: elem idx = r*16 + cl
#pragma unroll
  for (int q = 0; q < 4; ++q) {
    u16x8 raw = *(const u16x8*)(mp + t * 32 + q * 8);
    int r = 2 * t + (q >> 1), cb = (q & 1) * 8;
    float* dp = s + r * 20 + cb;
    float4 f0, f1v;
    f0.x = __uint_as_float((unsigned)raw[0] << 16);
    f0.y = __uint_as_float((unsigned)raw[1] << 16);
    f0.z = __uint_as_float((unsigned)raw[2] << 16);
    f0.w = __uint_as_float((unsigned)raw[3] << 16);
    f1v.x = __uint_as_float((unsigned)raw[4] << 16);
    f1v.y = __uint_as_float((unsigned)raw[5] << 16);
    f1v.z = __uint_as_float((unsigned)raw[6] << 16);
    f1v.w = __uint_as_float((unsigned)raw[7] << 16);
    *(float4*)dp = f0;
    *(float4*)(dp + 4) = f1v;
  }
  __syncthreads();

  {  // row bits 0..4
    int c = t & 15, rg = t >> 4;
    float w[32];
#pragma unroll
    for (int j = 0; j < 32; ++j) {
      int r = rg * 32 + j;
      w[j] = s[r * 20 + c];
    }
    reg_fwht<32, 1>(w);
#pragma unroll
    for (int j = 0; j < 32; ++j) {
      int r = rg * 32 + j;
      s[r * 20 + c] = w[j];
    }
  }
  __syncthreads();

  {  // row bits 5..8
    int c = t & 15;
    float w[32];
#pragma unroll
    for (int k = 0; k < 2; ++k) {
      int b0 = (t >> 4) * 2 + k;
#pragma unroll
      for (int j4 = 0; j4 < 16; ++j4) {
        int r = b0 + 32 * j4;
        w[k * 16 + j4] = s[r * 20 + c];
      }
      reg_fwht<16, 1>(w + k * 16);
#pragma unroll
      for (int j4 = 0; j4 < 16; ++j4) {
        int r = b0 + 32 * j4;
        s[r * 20 + c] = w[k * 16 + j4];
      }
    }
  }
  __syncthreads();

  float S = red[0] + red[1] + red[2] + red[3];
  float scale = 1.0f / sqrtf(S * 2359296.0f);
#pragma unroll
  for (int u = 0; u < 5; ++u) {  // 288 rows * 4 f4-chunks = 1152
    int idx = t + u * 256;
    if (idx < 1152) {
      int r = idx >> 2, c4 = (idx & 3) * 4;
      const float* sp = s + r * 20 + c4;
      long gi = (long)r * 8192 + l0 + c4;
      float4 iv = *(const float4*)(initW + gi);
      ushort4 pk;
      pk.x = f2bf(iv.x + sp[0] * scale);
      pk.y = f2bf(iv.y + sp[1] * scale);
      pk.z = f2bf(iv.z + sp[2] * scale);
      pk.w = f2bf(iv.w + sp[3] * scale);
      *(ushort4*)(outW + gi) = pk;
    }
  }
}

// ---------------- gemm body: MFMA, in-block split-K + LDS reduce ------------
template <int NACC, int SPLITK, bool RELU, bool OUT_BF16>
__device__ __forceinline__ void gemm_body(
    const __hip_bfloat16* __restrict__ A, const __hip_bfloat16* __restrict__ B,
    const float* __restrict__ bias, void* __restrict__ C, int M, int N, int K,
    int bid, int tid, float* red) {
  int wave = tid >> 6, lane = tid & 63;
  int tileid = bid * (4 / SPLITK) + wave / SPLITK;
  int sk = wave % SPLITK;
  int ntiles = N / (16 * NACC);
  int mt = tileid / ntiles, nt = tileid % ntiles;
  int ml = lane & 15;
  int q = lane >> 4;
  const short* As = (const short*)A;
  const short* Bs = (const short*)B;
  long arow = (long)(mt * 16 + ml) * K + q * 8;
  int KS = K / SPLITK, k0 = sk * KS;
  f32x4 acc[NACC] = {};
  for (int k = k0; k < k0 + KS; k += 32) {
    bf16x8 av = *(const bf16x8*)(As + arow + k);
#pragma unroll
    for (int a = 0; a < NACC; ++a) {
      int n = nt * 16 * NACC + a * 16 + ml;
      bf16x8 bv = *(const bf16x8*)(Bs + (long)n * K + q * 8 + k);
      acc[a] = __builtin_amdgcn_mfma_f32_16x16x32_bf16(av, bv, acc[a], 0, 0, 0);
    }
  }
#pragma unroll
  for (int a = 0; a < NACC; ++a)
#pragma unroll
    for (int r = 0; r < 4; ++r)
      red[(wave * NACC + a) * 320 + lane * 5 + r] = acc[a][r];
  __syncthreads();
  if (sk == 0) {
#pragma unroll
    for (int a = 0; a < NACC; ++a) {
      int n = nt * 16 * NACC + a * 16 + ml;
      float bv = bias[n];
#pragma unroll
      for (int r = 0; r < 4; ++r) {
        float vv = bv;
#pragma unroll
        for (int j = 0; j < SPLITK; ++j)
          vv += red[((wave + j) * NACC + a) * 320 + lane * 5 + r];
        int mm = mt * 16 + q * 4 + r;
        if (RELU) vv = fmaxf(vv, 0.f);
        if (OUT_BF16)
          ((__hip_bfloat16*)C)[(long)mm * N + n] = __float2bfloat16(vv);
        else
          ((float*)C)[(long)mm * N + n] = vv;
      }
    }
  }
}

// ---------------- mega kernel v2: 512 blocks, 2 jobs/phase ------------------
// LDS 40960 B. __launch_bounds__(256,2) -> VGPR cap 256 (no spill; r4's
// failure was the (256,4) cap=64). Coop capacity: even at 2 blk/CU,
// 512 blocks fit -> launch always valid if compile-time resources allow.
__global__ __launch_bounds__(256, 2) void k_mega(FFParams p) {
  __shared__ __align__(16) float s[10240];
  float* red = s + 10236;
  int b = blockIdx.x, t = threadIdx.x;

  // phase 1a: xb slice (96 float4 per block; 512*96 = 49152 total)
  if (t < 96) {
    int id = b * 96 + t;
    float4 xv = ((const float4*)p.x)[id];
    ushort4 o;
    o.x = f2bf(xv.x);
    o.y = f2bf(xv.y);
    o.z = f2bf(xv.z);
    o.w = f2bf(xv.w);
    ((ushort4*)p.xb)[id] = o;
  }
  // phase 1b: two front pipe jobs
  front_pipe(p, b, t, s, red);
  __syncthreads();  // WAR: job1's tail reads of s/red vs job2's writes
  front_pipe(p, b + 512, t, s, red);
  // phase 1c: bias stragglers
  if (b == 0) {
    __syncthreads();
    bias1_job(p, t, s);
  } else if (b == 1) {
    __syncthreads();
    bias2_job(p, t, s);
  }

  cg::this_grid().sync();

  // phase 2: f2c, two jobs (j = b -> pipe0, j = b+512 -> pipe1)
  f2c_body(p.m4b, p.iW1, (unsigned short*)p.W1b, p.partial, b & 511, t, s,
           red);
  __syncthreads();  // WAR between jobs
  f2c_body(p.m4b + (long)LLW, p.iW2, (unsigned short*)p.W2b, p.partial + 512,
           b & 511, t, s, red);

  cg::this_grid().sync();

  // phase 3: gemm1 relu -> hb (NACC=6, SPLITK=4 -> exactly 512 tiles)
  gemm_body<6, 4, true, true>(p.xb, p.W1b, p.b1w, p.hb, 256, 3072, 768, b, t,
                              s);

  cg::this_grid().sync();

  // phase 4: gemm2 -> out (384 active blocks)
  if (b < 384)
    gemm_body<2, 4, false, false>(p.hb, p.W2b, p.b2w, p.out, 256, 768, 3072, b,
                                  t, s);
}

// ---------------- fallback standalone kernels (r5 proven chain) -------------
__global__ __launch_bounds__(256) void k_front_sa(FFParams p) {
  __shared__ __align__(16) float s[10240];
  float* red = s + 10236;
  int b = blockIdx.x, t = threadIdx.x;
  if (b == 0) {
    bias1_job(p, t, s);
  } else if (b == 1) {
    bias2_job(p, t, s);
  } else if (b < 1026) {
    front_pipe(p, b - 2, t, s, red);
  } else {
    int id0 = (b - 1026) * 256 + t;
#pragma unroll
    for (int it = 0; it < 2; ++it) {
      int id = id0 + it * 24576;
      float4 xv = ((const float4*)p.x)[id];
      ushort4 o;
      o.x = f2bf(xv.x);
      o.y = f2bf(xv.y);
      o.z = f2bf(xv.z);
      o.w = f2bf(xv.w);
      ((ushort4*)p.xb)[id] = o;
    }
  }
}

__global__ __launch_bounds__(256) void k_f2c_sa(FFParams p) {
  __shared__ __align__(16) float s[10240];
  float* red = s + 10236;
  int b = blockIdx.x, t = threadIdx.x;
  int pipe = b >> 9, lb = b & 511;
  f2c_body(p.m4b + (long)pipe * LLW, pipe ? p.iW2 : p.iW1,
           (unsigned short*)(pipe ? p.W2b : p.W1b), p.partial + pipe * 512, lb,
           t, s, red);
}

__global__ __launch_bounds__(256) void k_gemm1_sa(FFParams p) {
  __shared__ __align__(16) float s[5120];
  gemm_body<4, 2, true, true>(p.xb, p.W1b, p.b1w, p.hb, 256, 3072, 768,
                              blockIdx.x, threadIdx.x, s);
}

__global__ __launch_bounds__(256) void k_gemm2_sa(FFParams p) {
  __shared__ __align__(16) float s[2560];
  gemm_body<2, 4, false, false>(p.hb, p.W2b, p.b2w, p.out, 256, 768, 3072,
                                blockIdx.x, threadIdx.x, s);
}

// ---------------- workspace layout (bytes) ----------------------------------
#define OFF_PART 0                          // 1024 f32 partials
#define OFF_M2S 4096                        // (unused)
#define OFF_M4B (OFF_M2S + 16384)           // 2*LLW bf16 = 16 MiB
#define OFF_W1B (OFF_M4B + 2 * LLW * 2)     // 2359296 bf16
#define OFF_W2B (OFF_W1B + 4718592)
#define OFF_HB (OFF_W2B + 4718592)          // 256*3072 bf16
#define OFF_XB (OFF_HB + 1572864)           // 256*768 bf16
#define OFF_B1 (OFF_XB + 393216)            // 3072 f32
#define OFF_B2 (OFF_B1 + 12288)             // 768 f32

extern "C" void kernel_launch(void* const* d_in, const int* in_sizes, int n_in,
                              void* d_out, int out_size, void* d_ws,
                              size_t ws_size, hipStream_t stream) {
  char* ws = (char*)d_ws;
  FFParams p;
  p.x = (const float*)d_in[0];
  p.theta = (const float*)d_in[1];
  p.iW1 = (const float*)d_in[2];
  p.ib1 = (const float*)d_in[3];
  p.iW2 = (const float*)d_in[4];
  p.ib2 = (const float*)d_in[5];
  p.BB1 = (const float*)d_in[6];
  p.Pi1 = (const int*)d_in[7];
  p.GG1 = (const float*)d_in[8];
  p.BBb1 = (const float*)d_in[9];
  p.Pib1 = (const int*)d_in[10];
  p.GGb1 = (const float*)d_in[11];
  p.BB2 = (const float*)d_in[12];
  p.Pi2 = (const int*)d_in[13];
  p.GG2 = (const float*)d_in[14];
  p.BBb2 = (const float*)d_in[15];
  p.Pib2 = (const int*)d_in[16];
  p.GGb2 = (const float*)d_in[17];
  p.partial = (float*)(ws + OFF_PART);
  p.m4b = (unsigned short*)(ws + OFF_M4B);
  p.W1b = (__hip_bfloat16*)(ws + OFF_W1B);
  p.W2b = (__hip_bfloat16*)(ws + OFF_W2B);
  p.hb = (__hip_bfloat16*)(ws + OFF_HB);
  p.xb = (__hip_bfloat16*)(ws + OFF_XB);
  p.b1w = (float*)(ws + OFF_B1);
  p.b2w = (float*)(ws + OFF_B2);
  p.out = (float*)d_out;

  void* kargs[] = {(void*)&p};
  hipError_t e = hipLaunchCooperativeKernel((const void*)k_mega, dim3(512),
                                            dim3(256), kargs, 0, stream);
  if (e != hipSuccess) {
    (void)hipGetLastError();  // clear error; use proven multi-launch fallback
    k_front_sa<<<1122, 256, 0, stream>>>(p);
    k_f2c_sa<<<1024, 256, 0, stream>>>(p);
    k_gemm1_sa<<<384, 256, 0, stream>>>(p);
    k_gemm2_sa<<<384, 256, 0, stream>>>(p);
  }
}

// Round 7
// 225.609 us; speedup vs baseline: 1.9540x; 1.9540x over previous
//
#include <hip/hip_runtime.h>
#include <hip/hip_bf16.h>

typedef __attribute__((ext_vector_type(8))) short bf16x8;
typedef __attribute__((ext_vector_type(8))) unsigned short u16x8;
typedef __attribute__((ext_vector_type(4))) float f32x4;

#define LLW 4194304

// ---------------- param bundle ----------------------------------------------
struct FFParams {
  const float* BB1; const int* Pi1; const float* GG1;
  const float* BB2; const int* Pi2; const float* GG2;
  unsigned short* m4b; float* partial; float* m2s; const float* theta;
  const float* BBb1; const int* Pib1; const float* GGb1; const float* ib1;
  float* b1w;
  const float* BBb2; const int* Pib2; const float* GGb2; const float* ib2;
  float* b2w;
  const float* x; __hip_bfloat16* xb;
  const float* iW1; const float* iW2;
  __hip_bfloat16* W1b; __hip_bfloat16* W2b;
  __hip_bfloat16* hb; float* out;
};

// ---------------- in-register FWHT over N entries spaced S apart ------------
template <int N, int S>
__device__ __forceinline__ void reg_fwht(float* v) {
#pragma unroll
  for (int h = 1; h < N; h <<= 1)
#pragma unroll
    for (int g = 0; g < N; g += 2 * h)
#pragma unroll
      for (int j = 0; j < h; ++j) {
        float a = v[(g + j) * S], b = v[(g + j + h) * S];
        v[(g + j) * S] = a + b;
        v[(g + j + h) * S] = a - b;
      }
}

__device__ __forceinline__ unsigned short f2bf(float f) {
  unsigned u = __float_as_uint(f);
  unsigned r = (u + 0x7fff + ((u >> 16) & 1)) >> 16;
  return (unsigned short)r;
}

// generic barriered LDS FWHT (tiny bias2 only)
__device__ __forceinline__ void lds_fwht(float* s, int n, int tid, int T) {
  for (int h = 1; h < n; h <<= 1) {
    __syncthreads();
    for (int t = tid; t < (n >> 1); t += T) {
      int i0 = ((t & ~(h - 1)) << 1) | (t & (h - 1));
      int i1 = i0 + h;
      float a = s[i0], b = s[i1];
      s[i0] = a + b;
      s[i1] = a - b;
    }
  }
  __syncthreads();
}

// ---------------- register FWHT-2048 with 256 threads -----------------------
// pad: 2304 floats scratch; dst: 2048 floats output (must not alias pad)
__device__ __forceinline__ void fwht2048_block(float w[8], float* pad,
                                               float* dst, int t) {
  reg_fwht<8, 1>(w);  // bits 8..10
#pragma unroll
  for (int j = 0; j < 8; ++j) {
    int i = t + 256 * j;
    pad[i + 4 * (i >> 5)] = w[j];
  }
  __syncthreads();
  {  // bits 0..2
    int base = 8 * t + 4 * (t >> 2);
    float4 a = *(float4*)(pad + base);
    float4 b = *(float4*)(pad + base + 4);
    float u[8] = {a.x, a.y, a.z, a.w, b.x, b.y, b.z, b.w};
    reg_fwht<8, 1>(u);
    *(float4*)(pad + base) = make_float4(u[0], u[1], u[2], u[3]);
    *(float4*)(pad + base + 4) = make_float4(u[4], u[5], u[6], u[7]);
  }
  __syncthreads();
  {  // bits 3..5
    int b0 = (t & 7) + 64 * (t >> 3);
    float u[8];
#pragma unroll
    for (int j = 0; j < 8; ++j) {
      int i = b0 + 8 * j;
      u[j] = pad[i + 4 * (i >> 5)];
    }
    reg_fwht<8, 1>(u);
#pragma unroll
    for (int j = 0; j < 8; ++j) {
      int i = b0 + 8 * j;
      pad[i + 4 * (i >> 5)] = u[j];
    }
  }
  __syncthreads();
  // bits 6..7 -> dst unpadded
#pragma unroll
  for (int g = 0; g < 2; ++g) {
    int b0 = (t & 63) + 256 * ((g << 2) | (t >> 6));
    float u[4];
#pragma unroll
    for (int j = 0; j < 4; ++j) {
      int i = b0 + 64 * j;
      u[j] = pad[i + 4 * (i >> 5)];
    }
    reg_fwht<4, 1>(u);
#pragma unroll
    for (int j = 0; j < 4; ++j) dst[b0 + 64 * j] = u[j];
  }
  __syncthreads();
}

// ---------------- bias1: LL=4096, K=2048, DD=3072 (uses s[0..8191]) ---------
__device__ __forceinline__ void bias1_job(const FFParams& p, int t, float* s) {
  float* tabd = s + 6144;
  float w[8];
#pragma unroll
  for (int j = 0; j < 8; ++j) {
    int i = t + 256 * j;
    w[j] = p.BBb1[i] * p.theta[i];
  }
  fwht2048_block(w, s, tabd, t);

  float w16[16];
  float lsum = 0.f;
#pragma unroll
  for (int j = 0; j < 16; ++j) {
    int i = t + 256 * j;
    float g = p.GGb1[i];
    lsum += g * g;
    w16[j] = tabd[p.Pib1[i] & 2047] * g;
  }
  reg_fwht<16, 1>(w16);  // bits 8..11
#pragma unroll
  for (int j = 0; j < 16; ++j) {
    int i = t + 256 * j;
    s[i + 4 * (i >> 5)] = w16[j];
  }
  for (int off = 32; off; off >>= 1) lsum += __shfl_down(lsum, off, 64);
  if ((t & 63) == 0) s[4608 + (t >> 6)] = lsum;
  __syncthreads();
  float S = s[4608] + s[4609] + s[4610] + s[4611];
  {  // bits 0..3
    int base16 = 16 * t + 4 * (t >> 1);
    float u[16];
#pragma unroll
    for (int q = 0; q < 4; ++q) {
      float4 r = *(float4*)(s + base16 + q * 4);
      u[q * 4 + 0] = r.x;
      u[q * 4 + 1] = r.y;
      u[q * 4 + 2] = r.z;
      u[q * 4 + 3] = r.w;
    }
    reg_fwht<16, 1>(u);
#pragma unroll
    for (int q = 0; q < 4; ++q)
      *(float4*)(s + base16 + q * 4) =
          make_float4(u[q * 4], u[q * 4 + 1], u[q * 4 + 2], u[q * 4 + 3]);
  }
  __syncthreads();
  {  // bits 4..7 + epilogue
    float scale = 1.0f / sqrtf(S * 3072.0f);
    int b0 = (t & 15) + 256 * (t >> 4);
    float u[16];
#pragma unroll
    for (int j = 0; j < 16; ++j) {
      int i = b0 + 16 * j;
      u[j] = s[i + 4 * (i >> 5)];
    }
    reg_fwht<16, 1>(u);
#pragma unroll
    for (int j = 0; j < 16; ++j) {
      int i = b0 + 16 * j;
      if (i < 3072) p.b1w[i] = p.ib1[i] + u[j] * scale;
    }
  }
}

// ---------------- bias2: LL=1024, K=1024, DD=768 (uses s[0..2051]) ----------
__device__ __forceinline__ void bias2_job(const FFParams& p, int t, float* s) {
  float* tab2 = s;
  float* m42 = s + 1024;
  for (int i = t; i < 1024; i += 256) tab2[i] = p.BBb2[i] * p.theta[i];
  lds_fwht(tab2, 1024, t, 256);
  float lsum = 0.f;
  for (int i = t; i < 1024; i += 256) {
    float g = p.GGb2[i];
    lsum += g * g;
    m42[i] = tab2[p.Pib2[i] & 1023] * g;
  }
  for (int off = 32; off; off >>= 1) lsum += __shfl_down(lsum, off, 64);
  if ((t & 63) == 0) s[2048 + (t >> 6)] = lsum;
  lds_fwht(m42, 1024, t, 256);
  float S = s[2048] + s[2049] + s[2050] + s[2051];
  float scale = 1.0f / sqrtf(S * 768.0f);
  for (int i = t; i < 768; i += 256) p.b2w[i] = p.ib2[i] + m42[i] * scale;
}

// ---------------- k_pre: m2 tables (b 0,1), biases (b 2,3), xb (b 4..99) ----
// Everything not on the front critical path, so k_front is EXACTLY 1024
// uniform pipe blocks (one co-resident scheduling round at 4 blk/CU).
__global__ __launch_bounds__(256) void k_pre(FFParams p) {
  __shared__ __align__(16) float s[9216];
  int b = blockIdx.x, t = threadIdx.x;
  if (b < 2) {
    const float* BB = b ? p.BB2 : p.BB1;
    float w[8];
#pragma unroll
    for (int j = 0; j < 8; ++j) {
      int i = t + 256 * j;
      w[j] = BB[i] * p.theta[i];
    }
    fwht2048_block(w, s + 2304, s, t);  // dst s[0:2048] scratch-only
    // re-do with dst = global? cheaper: write from s
    for (int i = t; i < 2048; i += 256) p.m2s[b * 2048 + i] = s[i];
  } else if (b == 2) {
    bias1_job(p, t, s);
  } else if (b == 3) {
    bias2_job(p, t, s);
  } else {
    int id0 = (b - 4) * 256 + t;
#pragma unroll
    for (int it = 0; it < 2; ++it) {
      int id = id0 + it * 24576;
      float4 xv = ((const float4*)p.x)[id];
      ushort4 o;
      o.x = f2bf(xv.x);
      o.y = f2bf(xv.y);
      o.z = f2bf(xv.z);
      o.w = f2bf(xv.w);
      ((ushort4*)p.xb)[id] = o;
    }
  }
}

// ---------------- k_front: EXACTLY 1024 uniform pipe blocks -----------------
// m2 table loaded from global (L2-broadcast). m4b written TRANSPOSED by
// 16-col groups: elem (chunk r, pos c) at (c>>4)*8192 + r*16 + (c&15).
__global__ __launch_bounds__(256) void k_front(FFParams p) {
  __shared__ __align__(16) float s[9216];
  __shared__ float red[4];
  int b = blockIdx.x, t = threadIdx.x;
  int pipe = b >> 9, chunk = b & 511;
  const int* Pi = pipe ? p.Pi2 : p.Pi1;
  const float* GG = pipe ? p.GG2 : p.GG1;
  const float* mm = p.m2s + pipe * 2048;
  for (int u = t; u < 512; u += 256) ((float4*)s)[u] = ((const float4*)mm)[u];
  __syncthreads();

  long base = (long)chunk * 8192;
  const int4* p4 = (const int4*)(Pi + base);
  const float4* g4 = (const float4*)(GG + base);
  float v[32];
  float lsum = 0.f;
#pragma unroll
  for (int j = 0; j < 8; ++j) {  // i = t*4 + e + j*1024
    int4 pp = p4[t + j * 256];
    float4 g = g4[t + j * 256];
    lsum += g.x * g.x + g.y * g.y + g.z * g.z + g.w * g.w;
    v[j * 4 + 0] = s[pp.x & 2047] * g.x;
    v[j * 4 + 1] = s[pp.y & 2047] * g.y;
    v[j * 4 + 2] = s[pp.z & 2047] * g.z;
    v[j * 4 + 3] = s[pp.w & 2047] * g.w;
  }
  for (int off = 32; off; off >>= 1) lsum += __shfl_down(lsum, off, 64);
  if ((t & 63) == 0) red[t >> 6] = lsum;

#pragma unroll
  for (int e = 0; e < 4; ++e) reg_fwht<8, 4>(v + e);  // bits 10..12

  __syncthreads();  // tab reads + red writes complete; s reusable
  if (t == 0)
    p.partial[pipe * 512 + chunk] = red[0] + red[1] + red[2] + red[3];

#pragma unroll
  for (int j = 0; j < 8; ++j) {
    int A = t * 4 + 4 * (t >> 3) + j * 1152;
    *(float4*)(s + A) =
        make_float4(v[j * 4], v[j * 4 + 1], v[j * 4 + 2], v[j * 4 + 3]);
  }
  __syncthreads();
  {  // bits 5..9
    int b0 = (t & 31) + (t >> 5) * 1024;
    float w[32];
#pragma unroll
    for (int j2 = 0; j2 < 32; ++j2) {
      int i = b0 + j2 * 32;
      w[j2] = s[i + 4 * (i >> 5)];
    }
    reg_fwht<32, 1>(w);
#pragma unroll
    for (int j2 = 0; j2 < 32; ++j2) {
      int i = b0 + j2 * 32;
      s[i + 4 * (i >> 5)] = w[j2];
    }
  }
  __syncthreads();
  // bits 0..4: thread owns c = t*32..t*32+31 (contiguous)
#pragma unroll
  for (int q = 0; q < 8; ++q) {
    float4 r = *(const float4*)(s + t * 36 + q * 4);
    v[q * 4 + 0] = r.x;
    v[q * 4 + 1] = r.y;
    v[q * 4 + 2] = r.z;
    v[q * 4 + 3] = r.w;
  }
  reg_fwht<32, 1>(v);
  // transposed write: col-groups 2t, 2t+1; 32B per group
  unsigned short* o = p.m4b + (long)pipe * LLW;
  long a0 = (long)(2 * t) * 8192 + (long)chunk * 16;
#pragma unroll
  for (int q = 0; q < 4; ++q) {
    u16x8 pk;
#pragma unroll
    for (int e = 0; e < 8; ++e) pk[e] = f2bf(v[q * 8 + e]);
    *(u16x8*)(o + a0 + (q >> 1) * 8192 + (q & 1) * 8) = pk;
  }
}

// ---------------- k_f2c: FWHT over bits 13..21 + epilogue, both pipes -------
// Verified padded layout: idx(r,c) = r*20 + (r>>5)*16 + c (max 10475).
// col-group swizzle g: pairs (2m,2m+1) share an initW cache line and land on
// the same XCD (blockIdx%8) for L2 reuse.
__global__ __launch_bounds__(256) void k_f2c(FFParams p) {
  __shared__ __align__(16) float s[10480];
  __shared__ float red[4];
  int b = blockIdx.x, t = threadIdx.x;
  int pipe = b >> 9;
  int lb = b & 511;
  int g = ((lb & 7) << 6) | (lb >> 3);
  int l0 = g * 16;
  const unsigned short* mp = p.m4b + (long)pipe * LLW + (long)g * 8192;
  const float* initW = pipe ? p.iW2 : p.iW1;
  unsigned short* outW = (unsigned short*)(pipe ? p.W2b : p.W1b);
  const float* partial_p = p.partial + pipe * 512;

  // reduce the 512 per-block sum(GG^2) partials (L2-hot) -> red[]
  {
    float ps = partial_p[t] + partial_p[256 + t];
    for (int off = 32; off; off >>= 1) ps += __shfl_down(ps, off, 64);
    if ((t & 63) == 0) red[t >> 6] = ps;
  }

  // contiguous 16KB read: elem idx = r*16 + cl
#pragma unroll
  for (int q = 0; q < 4; ++q) {
    u16x8 raw = *(const u16x8*)(mp + t * 32 + q * 8);
    int r = 2 * t + (q >> 1), cb = (q & 1) * 8;
    float* dp = s + r * 20 + (r >> 5) * 16 + cb;
    float4 f0, f1v;
    f0.x = __uint_as_float((unsigned)raw[0] << 16);
    f0.y = __uint_as_float((unsigned)raw[1] << 16);
    f0.z = __uint_as_float((unsigned)raw[2] << 16);
    f0.w = __uint_as_float((unsigned)raw[3] << 16);
    f1v.x = __uint_as_float((unsigned)raw[4] << 16);
    f1v.y = __uint_as_float((unsigned)raw[5] << 16);
    f1v.z = __uint_as_float((unsigned)raw[6] << 16);
    f1v.w = __uint_as_float((unsigned)raw[7] << 16);
    *(float4*)dp = f0;
    *(float4*)(dp + 4) = f1v;
  }
  __syncthreads();

  {  // row bits 0..4
    int c = t & 15, rg = t >> 4;
    float w[32];
#pragma unroll
    for (int j = 0; j < 32; ++j) {
      int r = rg * 32 + j;
      w[j] = s[r * 20 + (r >> 5) * 16 + c];
    }
    reg_fwht<32, 1>(w);
#pragma unroll
    for (int j = 0; j < 32; ++j) {
      int r = rg * 32 + j;
      s[r * 20 + (r >> 5) * 16 + c] = w[j];
    }
  }
  __syncthreads();

  {  // row bits 5..8
    int c = t & 15;
    float w[32];
#pragma unroll
    for (int k = 0; k < 2; ++k) {
      int b0 = (t >> 4) * 2 + k;
#pragma unroll
      for (int j4 = 0; j4 < 16; ++j4) {
        int r = b0 + 32 * j4;
        w[k * 16 + j4] = s[r * 20 + (r >> 5) * 16 + c];
      }
      reg_fwht<16, 1>(w + k * 16);
#pragma unroll
      for (int j4 = 0; j4 < 16; ++j4) {
        int r = b0 + 32 * j4;
        s[r * 20 + (r >> 5) * 16 + c] = w[k * 16 + j4];
      }
    }
  }
  __syncthreads();

  float S = red[0] + red[1] + red[2] + red[3];
  float scale = 1.0f / sqrtf(S * 2359296.0f);
#pragma unroll
  for (int u = 0; u < 5; ++u) {  // 288 rows * 4 f4-chunks = 1152
    int idx = t + u * 256;
    if (idx < 1152) {
      int r = idx >> 2, c4 = (idx & 3) * 4;
      const float* sp = s + r * 20 + (r >> 5) * 16 + c4;
      long gi = (long)r * 8192 + l0 + c4;
      float4 iv = *(const float4*)(initW + gi);
      ushort4 pk;
      pk.x = f2bf(iv.x + sp[0] * scale);
      pk.y = f2bf(iv.y + sp[1] * scale);
      pk.z = f2bf(iv.z + sp[2] * scale);
      pk.w = f2bf(iv.w + sp[3] * scale);
      *(ushort4*)(outW + gi) = pk;
    }
  }
}

// ---------------- MFMA GEMM, in-block split-K + LDS reduce ------------------
// grid must be exactly (M/16)*(N/16/NACC)*SPLITK/4 blocks of 256 threads.
template <int NACC, int SPLITK, bool RELU, bool OUT_BF16>
__global__ __launch_bounds__(256) void k_gemm(
    const __hip_bfloat16* __restrict__ A, const __hip_bfloat16* __restrict__ B,
    const float* __restrict__ bias, void* __restrict__ C, int M, int N, int K) {
  __shared__ float red[4 * NACC * 320];  // [wave][acc][lane*5+r], pad 5
  int wave = threadIdx.x >> 6, lane = threadIdx.x & 63;
  int tileid = blockIdx.x * (4 / SPLITK) + wave / SPLITK;
  int sk = wave % SPLITK;
  int ntiles = N / (16 * NACC);
  int mt = tileid / ntiles, nt = tileid % ntiles;
  int ml = lane & 15;
  int q = lane >> 4;
  const short* As = (const short*)A;
  const short* Bs = (const short*)B;
  long arow = (long)(mt * 16 + ml) * K + q * 8;
  int KS = K / SPLITK, k0 = sk * KS;
  f32x4 acc[NACC] = {};
  for (int k = k0; k < k0 + KS; k += 32) {
    bf16x8 av = *(const bf16x8*)(As + arow + k);
#pragma unroll
    for (int a = 0; a < NACC; ++a) {
      int n = nt * 16 * NACC + a * 16 + ml;
      bf16x8 bv = *(const bf16x8*)(Bs + (long)n * K + q * 8 + k);
      acc[a] = __builtin_amdgcn_mfma_f32_16x16x32_bf16(av, bv, acc[a], 0, 0, 0);
    }
  }
#pragma unroll
  for (int a = 0; a < NACC; ++a)
#pragma unroll
    for (int r = 0; r < 4; ++r)
      red[(wave * NACC + a) * 320 + lane * 5 + r] = acc[a][r];
  __syncthreads();
  if (sk == 0) {
#pragma unroll
    for (int a = 0; a < NACC; ++a) {
      int n = nt * 16 * NACC + a * 16 + ml;
      float bv = bias[n];
#pragma unroll
      for (int r = 0; r < 4; ++r) {
        float vv = bv;
#pragma unroll
        for (int j = 0; j < SPLITK; ++j)
          vv += red[((wave + j) * NACC + a) * 320 + lane * 5 + r];
        int mm = mt * 16 + q * 4 + r;
        if (RELU) vv = fmaxf(vv, 0.f);
        if (OUT_BF16)
          ((__hip_bfloat16*)C)[(long)mm * N + n] = __float2bfloat16(vv);
        else
          ((float*)C)[(long)mm * N + n] = vv;
      }
    }
  }
}

// ---------------- workspace layout (bytes) ----------------------------------
#define OFF_PART 0                          // 1024 f32 partials
#define OFF_M2S 4096                        // 4096 f32 (2 tables)
#define OFF_M4B (OFF_M2S + 16384)           // 2*LLW bf16 = 16 MiB
#define OFF_W1B (OFF_M4B + 2 * LLW * 2)     // 2359296 bf16
#define OFF_W2B (OFF_W1B + 4718592)
#define OFF_HB (OFF_W2B + 4718592)          // 256*3072 bf16
#define OFF_XB (OFF_HB + 1572864)           // 256*768 bf16
#define OFF_B1 (OFF_XB + 393216)            // 3072 f32
#define OFF_B2 (OFF_B1 + 12288)             // 768 f32

extern "C" void kernel_launch(void* const* d_in, const int* in_sizes, int n_in,
                              void* d_out, int out_size, void* d_ws,
                              size_t ws_size, hipStream_t stream) {
  char* ws = (char*)d_ws;
  FFParams p;
  p.x = (const float*)d_in[0];
  p.theta = (const float*)d_in[1];
  p.iW1 = (const float*)d_in[2];
  p.ib1 = (const float*)d_in[3];
  p.iW2 = (const float*)d_in[4];
  p.ib2 = (const float*)d_in[5];
  p.BB1 = (const float*)d_in[6];
  p.Pi1 = (const int*)d_in[7];
  p.GG1 = (const float*)d_in[8];
  p.BBb1 = (const float*)d_in[9];
  p.Pib1 = (const int*)d_in[10];
  p.GGb1 = (const float*)d_in[11];
  p.BB2 = (const float*)d_in[12];
  p.Pi2 = (const int*)d_in[13];
  p.GG2 = (const float*)d_in[14];
  p.BBb2 = (const float*)d_in[15];
  p.Pib2 = (const int*)d_in[16];
  p.GGb2 = (const float*)d_in[17];
  p.partial = (float*)(ws + OFF_PART);
  p.m2s = (float*)(ws + OFF_M2S);
  p.m4b = (unsigned short*)(ws + OFF_M4B);
  p.W1b = (__hip_bfloat16*)(ws + OFF_W1B);
  p.W2b = (__hip_bfloat16*)(ws + OFF_W2B);
  p.hb = (__hip_bfloat16*)(ws + OFF_HB);
  p.xb = (__hip_bfloat16*)(ws + OFF_XB);
  p.b1w = (float*)(ws + OFF_B1);
  p.b2w = (float*)(ws + OFF_B2);
  p.out = (float*)d_out;

  // 1: off-critical-path prep (m2 tables, biases, x->bf16) -- 100 blocks
  k_pre<<<100, 256, 0, stream>>>(p);
  // 2: EXACTLY 1024 uniform pipe blocks (one scheduling round)
  k_front<<<1024, 256, 0, stream>>>(p);
  // 3: W1b + W2b (both pipes, exactly 1024 blocks)
  k_f2c<<<1024, 256, 0, stream>>>(p);
  // 4: h = relu(x @ W1^T + b1): 16*96 tiles, SPLITK=2 -> 768 blocks
  k_gemm<2, 2, true, true><<<768, 256, 0, stream>>>(p.xb, p.W1b, p.b1w, p.hb,
                                                    256, 3072, 768);
  // 5: out = h @ W2^T + b2: 16*48 tiles, SPLITK=4 -> 768 blocks
  k_gemm<1, 4, false, false><<<768, 256, 0, stream>>>(p.hb, p.W2b, p.b2w,
                                                      p.out, 256, 768, 3072);
}

// Round 8
// 218.687 us; speedup vs baseline: 2.0158x; 1.0317x over previous
//
#include <hip/hip_runtime.h>
#include <hip/hip_bf16.h>

typedef __attribute__((ext_vector_type(8))) short bf16x8;
typedef __attribute__((ext_vector_type(8))) unsigned short u16x8;
typedef __attribute__((ext_vector_type(4))) float f32x4;

// ---------------- in-register FWHT over N entries spaced S apart ------------
template <int N, int S>
__device__ __forceinline__ void reg_fwht(float* v) {
#pragma unroll
  for (int h = 1; h < N; h <<= 1)
#pragma unroll
    for (int g = 0; g < N; g += 2 * h)
#pragma unroll
      for (int j = 0; j < h; ++j) {
        float a = v[(g + j) * S], b = v[(g + j + h) * S];
        v[(g + j) * S] = a + b;
        v[(g + j + h) * S] = a - b;
      }
}

__device__ __forceinline__ unsigned short f2bf(float f) {
  unsigned u = __float_as_uint(f);
  unsigned r = (u + 0x7fff + ((u >> 16) & 1)) >> 16;
  return (unsigned short)r;
}

// generic barriered LDS FWHT (tiny bias2 only)
__device__ __forceinline__ void lds_fwht(float* s, int n, int tid, int T) {
  for (int h = 1; h < n; h <<= 1) {
    __syncthreads();
    for (int t = tid; t < (n >> 1); t += T) {
      int i0 = ((t & ~(h - 1)) << 1) | (t & (h - 1));
      int i1 = i0 + h;
      float a = s[i0], b = s[i1];
      s[i0] = a + b;
      s[i1] = a - b;
    }
  }
  __syncthreads();
}

// ---------------- register FWHT-2048 with 256 threads -----------------------
__device__ __forceinline__ void fwht2048_block(float w[8], float* pad,
                                               float* dst, int t) {
  reg_fwht<8, 1>(w);  // bits 8..10
#pragma unroll
  for (int j = 0; j < 8; ++j) {
    int i = t + 256 * j;
    pad[i + 4 * (i >> 5)] = w[j];
  }
  __syncthreads();
  {  // bits 0..2
    int base = 8 * t + 4 * (t >> 2);
    float4 a = *(float4*)(pad + base);
    float4 b = *(float4*)(pad + base + 4);
    float u[8] = {a.x, a.y, a.z, a.w, b.x, b.y, b.z, b.w};
    reg_fwht<8, 1>(u);
    *(float4*)(pad + base) = make_float4(u[0], u[1], u[2], u[3]);
    *(float4*)(pad + base + 4) = make_float4(u[4], u[5], u[6], u[7]);
  }
  __syncthreads();
  {  // bits 3..5
    int b0 = (t & 7) + 64 * (t >> 3);
    float u[8];
#pragma unroll
    for (int j = 0; j < 8; ++j) {
      int i = b0 + 8 * j;
      u[j] = pad[i + 4 * (i >> 5)];
    }
    reg_fwht<8, 1>(u);
#pragma unroll
    for (int j = 0; j < 8; ++j) {
      int i = b0 + 8 * j;
      pad[i + 4 * (i >> 5)] = u[j];
    }
  }
  __syncthreads();
  // bits 6..7 -> dst unpadded
#pragma unroll
  for (int g = 0; g < 2; ++g) {
    int b0 = (t & 63) + 256 * ((g << 2) | (t >> 6));
    float u[4];
#pragma unroll
    for (int j = 0; j < 4; ++j) {
      int i = b0 + 64 * j;
      u[j] = pad[i + 4 * (i >> 5)];
    }
    reg_fwht<4, 1>(u);
#pragma unroll
    for (int j = 0; j < 4; ++j) dst[b0 + 64 * j] = u[j];
  }
  __syncthreads();
}

// ---------------- k_pre: m2 tables (blocks 0,1) + x->bf16 (blocks 2..97) ----
__global__ __launch_bounds__(256) void k_pre(
    const float* __restrict__ theta, const float* __restrict__ BB0,
    const float* __restrict__ BB1, float* __restrict__ m2s,
    const float* __restrict__ x, __hip_bfloat16* __restrict__ xb) {
  __shared__ __align__(16) float pad[2304];
  int b = blockIdx.x, t = threadIdx.x;
  if (b < 2) {
    const float* BB = b ? BB1 : BB0;
    float w[8];
#pragma unroll
    for (int j = 0; j < 8; ++j) {
      int i = t + 256 * j;
      w[j] = BB[i] * theta[i];
    }
    fwht2048_block(w, pad, m2s + b * 2048, t);
  } else {
    int id0 = (b - 2) * 256 + t;
#pragma unroll
    for (int it = 0; it < 2; ++it) {
      int id = id0 + it * 24576;
      float4 xv = ((const float4*)x)[id];
      ushort4 o;
      o.x = f2bf(xv.x);
      o.y = f2bf(xv.y);
      o.z = f2bf(xv.z);
      o.w = f2bf(xv.w);
      ((ushort4*)xb)[id] = o;
    }
  }
}

#define LLW 4194304

// ---------------- k_front: biases (blocks 0,1) + f1 x2 pipes (2..1025) ------
// m4b written TRANSPOSED by 16-col groups: elem (chunk r, pos c) stored at
// (c>>4)*8192 + r*16 + (c&15)  -> k_f2c reads 16KB contiguous per block.
__global__ __launch_bounds__(256) void k_front(
    const int* __restrict__ Pi1, const float* __restrict__ GG1,
    const int* __restrict__ Pi2, const float* __restrict__ GG2,
    const float* __restrict__ m2s, unsigned short* __restrict__ m4b,
    float* __restrict__ partial, const float* __restrict__ theta,
    const float* __restrict__ BBb1, const int* __restrict__ Pib1,
    const float* __restrict__ GGb1, const float* __restrict__ ib1,
    float* __restrict__ b1w, const float* __restrict__ BBb2,
    const int* __restrict__ Pib2, const float* __restrict__ GGb2,
    const float* __restrict__ ib2, float* __restrict__ b2w) {
  __shared__ __align__(16) float s[9216];  // tab aliases s[0:2048]
  __shared__ float red[4];
  int b = blockIdx.x, t = threadIdx.x;

  if (b >= 2) {
    int bb = b - 2;
    int pipe = bb >> 9, chunk = bb & 511;
    const int* Pi = pipe ? Pi2 : Pi1;
    const float* GG = pipe ? GG2 : GG1;
    const float* mm = m2s + pipe * 2048;
    for (int u = t; u < 512; u += 256) ((float4*)s)[u] = ((const float4*)mm)[u];
    __syncthreads();

    long base = (long)chunk * 8192;
    const int4* p4 = (const int4*)(Pi + base);
    const float4* g4 = (const float4*)(GG + base);
    float v[32];
    float lsum = 0.f;
#pragma unroll
    for (int j = 0; j < 8; ++j) {  // i = t*4 + e + j*1024
      int4 p = p4[t + j * 256];
      float4 g = g4[t + j * 256];
      lsum += g.x * g.x + g.y * g.y + g.z * g.z + g.w * g.w;
      v[j * 4 + 0] = s[p.x & 2047] * g.x;
      v[j * 4 + 1] = s[p.y & 2047] * g.y;
      v[j * 4 + 2] = s[p.z & 2047] * g.z;
      v[j * 4 + 3] = s[p.w & 2047] * g.w;
    }
    for (int off = 32; off; off >>= 1) lsum += __shfl_down(lsum, off, 64);
    if ((t & 63) == 0) red[t >> 6] = lsum;

#pragma unroll
    for (int e = 0; e < 4; ++e) reg_fwht<8, 4>(v + e);  // bits 10..12

    __syncthreads();  // tab reads + red writes complete; s reusable
    if (t == 0) partial[pipe * 512 + chunk] = red[0] + red[1] + red[2] + red[3];

#pragma unroll
    for (int j = 0; j < 8; ++j) {
      int A = t * 4 + 4 * (t >> 3) + j * 1152;
      *(float4*)(s + A) =
          make_float4(v[j * 4], v[j * 4 + 1], v[j * 4 + 2], v[j * 4 + 3]);
    }
    __syncthreads();
    {  // bits 5..9
      int b0 = (t & 31) + (t >> 5) * 1024;
      float w[32];
#pragma unroll
      for (int j2 = 0; j2 < 32; ++j2) {
        int i = b0 + j2 * 32;
        w[j2] = s[i + 4 * (i >> 5)];
      }
      reg_fwht<32, 1>(w);
#pragma unroll
      for (int j2 = 0; j2 < 32; ++j2) {
        int i = b0 + j2 * 32;
        s[i + 4 * (i >> 5)] = w[j2];
      }
    }
    __syncthreads();
    // bits 0..4: thread owns c = t*32..t*32+31 (contiguous)
#pragma unroll
    for (int q = 0; q < 8; ++q) {
      float4 r = *(const float4*)(s + t * 36 + q * 4);
      v[q * 4 + 0] = r.x;
      v[q * 4 + 1] = r.y;
      v[q * 4 + 2] = r.z;
      v[q * 4 + 3] = r.w;
    }
    reg_fwht<32, 1>(v);
    // transposed write: col-groups 2t, 2t+1; 32B per group
    unsigned short* o = m4b + (long)pipe * LLW;
    long a0 = (long)(2 * t) * 8192 + (long)chunk * 16;
#pragma unroll
    for (int q = 0; q < 4; ++q) {
      u16x8 pk;
#pragma unroll
      for (int e = 0; e < 8; ++e) pk[e] = f2bf(v[q * 8 + e]);
      *(u16x8*)(o + a0 + (q >> 1) * 8192 + (q & 1) * 8) = pk;
    }
  } else if (b == 0) {
    // ---- bias1: LL=4096, K=2048, DD=3072 ----
    float* tabd = s + 6144;
    float w[8];
#pragma unroll
    for (int j = 0; j < 8; ++j) {
      int i = t + 256 * j;
      w[j] = BBb1[i] * theta[i];
    }
    fwht2048_block(w, s, tabd, t);

    float w16[16];
    float lsum = 0.f;
#pragma unroll
    for (int j = 0; j < 16; ++j) {
      int i = t + 256 * j;
      float g = GGb1[i];
      lsum += g * g;
      w16[j] = tabd[Pib1[i] & 2047] * g;
    }
    reg_fwht<16, 1>(w16);  // bits 8..11
#pragma unroll
    for (int j = 0; j < 16; ++j) {
      int i = t + 256 * j;
      s[i + 4 * (i >> 5)] = w16[j];
    }
    for (int off = 32; off; off >>= 1) lsum += __shfl_down(lsum, off, 64);
    if ((t & 63) == 0) s[4608 + (t >> 6)] = lsum;
    __syncthreads();
    float S = s[4608] + s[4609] + s[4610] + s[4611];
    {  // bits 0..3
      int base16 = 16 * t + 4 * (t >> 1);
      float u[16];
#pragma unroll
      for (int q = 0; q < 4; ++q) {
        float4 r = *(float4*)(s + base16 + q * 4);
        u[q * 4 + 0] = r.x;
        u[q * 4 + 1] = r.y;
        u[q * 4 + 2] = r.z;
        u[q * 4 + 3] = r.w;
      }
      reg_fwht<16, 1>(u);
#pragma unroll
      for (int q = 0; q < 4; ++q)
        *(float4*)(s + base16 + q * 4) =
            make_float4(u[q * 4], u[q * 4 + 1], u[q * 4 + 2], u[q * 4 + 3]);
    }
    __syncthreads();
    {  // bits 4..7 + epilogue
      float scale = 1.0f / sqrtf(S * 3072.0f);
      int b0 = (t & 15) + 256 * (t >> 4);
      float u[16];
#pragma unroll
      for (int j = 0; j < 16; ++j) {
        int i = b0 + 16 * j;
        u[j] = s[i + 4 * (i >> 5)];
      }
      reg_fwht<16, 1>(u);
#pragma unroll
      for (int j = 0; j < 16; ++j) {
        int i = b0 + 16 * j;
        if (i < 3072) b1w[i] = ib1[i] + u[j] * scale;
      }
    }
  } else {
    // ---- bias2: LL=1024, K=1024, DD=768 ----
    float* tab2 = s;
    float* m42 = s + 1024;
    for (int i = t; i < 1024; i += 256) tab2[i] = BBb2[i] * theta[i];
    lds_fwht(tab2, 1024, t, 256);
    float lsum = 0.f;
    for (int i = t; i < 1024; i += 256) {
      float g = GGb2[i];
      lsum += g * g;
      m42[i] = tab2[Pib2[i] & 1023] * g;
    }
    for (int off = 32; off; off >>= 1) lsum += __shfl_down(lsum, off, 64);
    if ((t & 63) == 0) s[2048 + (t >> 6)] = lsum;
    lds_fwht(m42, 1024, t, 256);
    float S = s[2048] + s[2049] + s[2050] + s[2051];
    float scale = 1.0f / sqrtf(S * 768.0f);
    for (int i = t; i < 768; i += 256) b2w[i] = ib2[i] + m42[i] * scale;
  }
}

// ---------------- k_f2c: FWHT over bits 13..21 + epilogue, both pipes -------
// col-group swizzle g: pairs (2m,2m+1) share an initW cache line and land on
// the same XCD (blockIdx%8) for L2 reuse.
__global__ __launch_bounds__(256) void k_f2c(
    const unsigned short* __restrict__ m4b, const float* __restrict__ iW1,
    const float* __restrict__ iW2, const float* __restrict__ partial,
    __hip_bfloat16* __restrict__ W1b, __hip_bfloat16* __restrict__ W2b) {
  __shared__ __align__(16) float s[10480];
  __shared__ float red[4];
  int b = blockIdx.x, t = threadIdx.x;
  int pipe = b >> 9;
  int lb = b & 511;
  int g = ((lb & 7) << 6) | (lb >> 3);
  int l0 = g * 16;
  const unsigned short* mp = m4b + (long)pipe * LLW + (long)g * 8192;
  const float* initW = pipe ? iW2 : iW1;
  unsigned short* outW = (unsigned short*)(pipe ? W2b : W1b);

  // reduce the 512 per-block sum(GG^2) partials (L2-hot) -> red[]
  {
    float ps = partial[pipe * 512 + t] + partial[pipe * 512 + 256 + t];
    for (int off = 32; off; off >>= 1) ps += __shfl_down(ps, off, 64);
    if ((t & 63) == 0) red[t >> 6] = ps;
  }

  // contiguous 16KB read: elem idx = r*16 + cl
#pragma unroll
  for (int q = 0; q < 4; ++q) {
    u16x8 raw = *(const u16x8*)(mp + t * 32 + q * 8);
    int r = 2 * t + (q >> 1), cb = (q & 1) * 8;
    float* dp = s + r * 20 + (r >> 5) * 16 + cb;
    float4 f0, f1v;
    f0.x = __uint_as_float((unsigned)raw[0] << 16);
    f0.y = __uint_as_float((unsigned)raw[1] << 16);
    f0.z = __uint_as_float((unsigned)raw[2] << 16);
    f0.w = __uint_as_float((unsigned)raw[3] << 16);
    f1v.x = __uint_as_float((unsigned)raw[4] << 16);
    f1v.y = __uint_as_float((unsigned)raw[5] << 16);
    f1v.z = __uint_as_float((unsigned)raw[6] << 16);
    f1v.w = __uint_as_float((unsigned)raw[7] << 16);
    *(float4*)dp = f0;
    *(float4*)(dp + 4) = f1v;
  }
  __syncthreads();

  {  // row bits 0..4
    int c = t & 15, rg = t >> 4;
    float w[32];
#pragma unroll
    for (int j = 0; j < 32; ++j) {
      int r = rg * 32 + j;
      w[j] = s[r * 20 + (r >> 5) * 16 + c];
    }
    reg_fwht<32, 1>(w);
#pragma unroll
    for (int j = 0; j < 32; ++j) {
      int r = rg * 32 + j;
      s[r * 20 + (r >> 5) * 16 + c] = w[j];
    }
  }
  __syncthreads();

  {  // row bits 5..8
    int c = t & 15;
    float w[32];
#pragma unroll
    for (int k = 0; k < 2; ++k) {
      int b0 = (t >> 4) * 2 + k;
#pragma unroll
      for (int j4 = 0; j4 < 16; ++j4) {
        int r = b0 + 32 * j4;
        w[k * 16 + j4] = s[r * 20 + (r >> 5) * 16 + c];
      }
      reg_fwht<16, 1>(w + k * 16);
#pragma unroll
      for (int j4 = 0; j4 < 16; ++j4) {
        int r = b0 + 32 * j4;
        s[r * 20 + (r >> 5) * 16 + c] = w[k * 16 + j4];
      }
    }
  }
  __syncthreads();

  float S = red[0] + red[1] + red[2] + red[3];
  float scale = 1.0f / sqrtf(S * 2359296.0f);
#pragma unroll
  for (int u = 0; u < 5; ++u) {  // 288 rows * 4 f4-chunks = 1152
    int idx = t + u * 256;
    if (idx < 1152) {
      int r = idx >> 2, c4 = (idx & 3) * 4;
      const float* sp = s + r * 20 + (r >> 5) * 16 + c4;
      long gi = (long)r * 8192 + l0 + c4;
      float4 iv = *(const float4*)(initW + gi);
      ushort4 pk;
      pk.x = f2bf(iv.x + sp[0] * scale);
      pk.y = f2bf(iv.y + sp[1] * scale);
      pk.z = f2bf(iv.z + sp[2] * scale);
      pk.w = f2bf(iv.w + sp[3] * scale);
      *(ushort4*)(outW + gi) = pk;
    }
  }
}

// ---------------- MFMA GEMM, in-block split-K + LDS reduce ------------------
// grid must be exactly (M/16)*(N/16/NACC)*SPLITK/4 blocks of 256 threads.
template <int NACC, int SPLITK, bool RELU, bool OUT_BF16>
__global__ __launch_bounds__(256) void k_gemm(
    const __hip_bfloat16* __restrict__ A, const __hip_bfloat16* __restrict__ B,
    const float* __restrict__ bias, void* __restrict__ C, int M, int N, int K) {
  __shared__ float red[4 * NACC * 320];  // [wave][acc][lane*5+r], pad 5
  int wave = threadIdx.x >> 6, lane = threadIdx.x & 63;
  int tileid = blockIdx.x * (4 / SPLITK) + wave / SPLITK;
  int sk = wave % SPLITK;
  int ntiles = N / (16 * NACC);
  int mt = tileid / ntiles, nt = tileid % ntiles;
  int ml = lane & 15;
  int q = lane >> 4;
  const short* As = (const short*)A;
  const short* Bs = (const short*)B;
  long arow = (long)(mt * 16 + ml) * K + q * 8;
  int KS = K / SPLITK, k0 = sk * KS;
  f32x4 acc[NACC] = {};
  for (int k = k0; k < k0 + KS; k += 32) {
    bf16x8 av = *(const bf16x8*)(As + arow + k);
#pragma unroll
    for (int a = 0; a < NACC; ++a) {
      int n = nt * 16 * NACC + a * 16 + ml;
      bf16x8 bv = *(const bf16x8*)(Bs + (long)n * K + q * 8 + k);
      acc[a] = __builtin_amdgcn_mfma_f32_16x16x32_bf16(av, bv, acc[a], 0, 0, 0);
    }
  }
#pragma unroll
  for (int a = 0; a < NACC; ++a)
#pragma unroll
    for (int r = 0; r < 4; ++r)
      red[(wave * NACC + a) * 320 + lane * 5 + r] = acc[a][r];
  __syncthreads();
  if (sk == 0) {
#pragma unroll
    for (int a = 0; a < NACC; ++a) {
      int n = nt * 16 * NACC + a * 16 + ml;
      float bv = bias[n];
#pragma unroll
      for (int r = 0; r < 4; ++r) {
        float vv = bv;
#pragma unroll
        for (int j = 0; j < SPLITK; ++j)
          vv += red[((wave + j) * NACC + a) * 320 + lane * 5 + r];
        int mm = mt * 16 + q * 4 + r;
        if (RELU) vv = fmaxf(vv, 0.f);
        if (OUT_BF16)
          ((__hip_bfloat16*)C)[(long)mm * N + n] = __float2bfloat16(vv);
        else
          ((float*)C)[(long)mm * N + n] = vv;
      }
    }
  }
}

// ---------------- workspace layout (bytes) ----------------------------------
#define OFF_PART 0                          // 1024 f32 partials
#define OFF_M2S 4096
#define OFF_M4B (OFF_M2S + 16384)           // 2*LLW bf16 = 16 MiB
#define OFF_W1B (OFF_M4B + 2 * LLW * 2)     // 2359296 bf16
#define OFF_W2B (OFF_W1B + 4718592)
#define OFF_HB (OFF_W2B + 4718592)          // 256*3072 bf16
#define OFF_XB (OFF_HB + 1572864)           // 256*768 bf16
#define OFF_B1 (OFF_XB + 393216)            // 3072 f32
#define OFF_B2 (OFF_B1 + 12288)             // 768 f32

extern "C" void kernel_launch(void* const* d_in, const int* in_sizes, int n_in,
                              void* d_out, int out_size, void* d_ws,
                              size_t ws_size, hipStream_t stream) {
  const float* x = (const float*)d_in[0];
  const float* theta = (const float*)d_in[1];
  const float* iW1 = (const float*)d_in[2];
  const float* ib1 = (const float*)d_in[3];
  const float* iW2 = (const float*)d_in[4];
  const float* ib2 = (const float*)d_in[5];
  const float* BB_W1 = (const float*)d_in[6];
  const int* Pi_W1 = (const int*)d_in[7];
  const float* GG_W1 = (const float*)d_in[8];
  const float* BB_b1 = (const float*)d_in[9];
  const int* Pi_b1 = (const int*)d_in[10];
  const float* GG_b1 = (const float*)d_in[11];
  const float* BB_W2 = (const float*)d_in[12];
  const int* Pi_W2 = (const int*)d_in[13];
  const float* GG_W2 = (const float*)d_in[14];
  const float* BB_b2 = (const float*)d_in[15];
  const int* Pi_b2 = (const int*)d_in[16];
  const float* GG_b2 = (const float*)d_in[17];

  char* ws = (char*)d_ws;
  float* partial = (float*)(ws + OFF_PART);
  float* m2s = (float*)(ws + OFF_M2S);
  unsigned short* m4b = (unsigned short*)(ws + OFF_M4B);
  __hip_bfloat16* W1b = (__hip_bfloat16*)(ws + OFF_W1B);
  __hip_bfloat16* W2b = (__hip_bfloat16*)(ws + OFF_W2B);
  __hip_bfloat16* hb = (__hip_bfloat16*)(ws + OFF_HB);
  __hip_bfloat16* xb = (__hip_bfloat16*)(ws + OFF_XB);
  float* b1w = (float*)(ws + OFF_B1);
  float* b2w = (float*)(ws + OFF_B2);

  k_pre<<<98, 256, 0, stream>>>(theta, BB_W1, BB_W2, m2s, x, xb);
  k_front<<<1026, 256, 0, stream>>>(Pi_W1, GG_W1, Pi_W2, GG_W2, m2s, m4b,
                                    partial, theta, BB_b1, Pi_b1, GG_b1, ib1,
                                    b1w, BB_b2, Pi_b2, GG_b2, ib2, b2w);
  k_f2c<<<1024, 256, 0, stream>>>(m4b, iW1, iW2, partial, W1b, W2b);
  // h = relu(x @ W1^T + b1): 16*96 tiles, SPLITK=2 -> 768 blocks
  k_gemm<2, 2, true, true><<<768, 256, 0, stream>>>(xb, W1b, b1w, hb, 256,
                                                    3072, 768);
  // out = h @ W2^T + b2: 16*48 tiles, SPLITK=4 -> 768 blocks
  k_gemm<1, 4, false, false><<<768, 256, 0, stream>>>(hb, W2b, b2w, d_out, 256,
                                                      768, 3072);
}

// Round 9
// 215.317 us; speedup vs baseline: 2.0474x; 1.0157x over previous
//
#include <hip/hip_runtime.h>
#include <hip/hip_bf16.h>

typedef __attribute__((ext_vector_type(8))) short bf16x8;
typedef __attribute__((ext_vector_type(8))) unsigned short u16x8;
typedef __attribute__((ext_vector_type(4))) float f32x4;

#define LLW 4194304

// ---------------- in-register FWHT over N entries spaced S apart ------------
template <int N, int S>
__device__ __forceinline__ void reg_fwht(float* v) {
#pragma unroll
  for (int h = 1; h < N; h <<= 1)
#pragma unroll
    for (int g = 0; g < N; g += 2 * h)
#pragma unroll
      for (int j = 0; j < h; ++j) {
        float a = v[(g + j) * S], b = v[(g + j + h) * S];
        v[(g + j) * S] = a + b;
        v[(g + j + h) * S] = a - b;
      }
}

__device__ __forceinline__ unsigned short f2bf(float f) {
  unsigned u = __float_as_uint(f);
  unsigned r = (u + 0x7fff + ((u >> 16) & 1)) >> 16;
  return (unsigned short)r;
}

// generic barriered LDS FWHT (tiny bias2 only)
__device__ __forceinline__ void lds_fwht(float* s, int n, int tid, int T) {
  for (int h = 1; h < n; h <<= 1) {
    __syncthreads();
    for (int t = tid; t < (n >> 1); t += T) {
      int i0 = ((t & ~(h - 1)) << 1) | (t & (h - 1));
      int i1 = i0 + h;
      float a = s[i0], b = s[i1];
      s[i0] = a + b;
      s[i1] = a - b;
    }
  }
  __syncthreads();
}

// ---------------- register FWHT-2048 with 256 threads -----------------------
// pad: 2304 floats scratch; dst: 2048 floats output (must not alias pad)
__device__ __forceinline__ void fwht2048_block(float w[8], float* pad,
                                               float* dst, int t) {
  reg_fwht<8, 1>(w);  // bits 8..10
#pragma unroll
  for (int j = 0; j < 8; ++j) {
    int i = t + 256 * j;
    pad[i + 4 * (i >> 5)] = w[j];
  }
  __syncthreads();
  {  // bits 0..2
    int base = 8 * t + 4 * (t >> 2);
    float4 a = *(float4*)(pad + base);
    float4 b = *(float4*)(pad + base + 4);
    float u[8] = {a.x, a.y, a.z, a.w, b.x, b.y, b.z, b.w};
    reg_fwht<8, 1>(u);
    *(float4*)(pad + base) = make_float4(u[0], u[1], u[2], u[3]);
    *(float4*)(pad + base + 4) = make_float4(u[4], u[5], u[6], u[7]);
  }
  __syncthreads();
  {  // bits 3..5
    int b0 = (t & 7) + 64 * (t >> 3);
    float u[8];
#pragma unroll
    for (int j = 0; j < 8; ++j) {
      int i = b0 + 8 * j;
      u[j] = pad[i + 4 * (i >> 5)];
    }
    reg_fwht<8, 1>(u);
#pragma unroll
    for (int j = 0; j < 8; ++j) {
      int i = b0 + 8 * j;
      pad[i + 4 * (i >> 5)] = u[j];
    }
  }
  __syncthreads();
  // bits 6..7 -> dst unpadded
#pragma unroll
  for (int g = 0; g < 2; ++g) {
    int b0 = (t & 63) + 256 * ((g << 2) | (t >> 6));
    float u[4];
#pragma unroll
    for (int j = 0; j < 4; ++j) {
      int i = b0 + 64 * j;
      u[j] = pad[i + 4 * (i >> 5)];
    }
    reg_fwht<4, 1>(u);
#pragma unroll
    for (int j = 0; j < 4; ++j) dst[b0 + 64 * j] = u[j];
  }
  __syncthreads();
}

// ---------------- k_front: xb 0..95, bias1=96, bias2=97, pipes 98..1121 -----
// Light xb blocks FIRST so the >1024 stragglers are cheap xb blocks, never
// 10us pipe blocks. Pipe blocks: (1) issue all 16 Pi/GG HBM loads into VGPRs
// (not drained by barriers), (2) compute m2 in-block (fwht2048, ~us of
// compute = latency-hiding window), (3) gather with landed registers.
__global__ __launch_bounds__(256, 4) void k_front(
    const float* __restrict__ BB1, const int* __restrict__ Pi1,
    const float* __restrict__ GG1, const float* __restrict__ BB2,
    const int* __restrict__ Pi2, const float* __restrict__ GG2,
    unsigned short* __restrict__ m4b, float* __restrict__ partial,
    const float* __restrict__ theta, const float* __restrict__ BBb1,
    const int* __restrict__ Pib1, const float* __restrict__ GGb1,
    const float* __restrict__ ib1, float* __restrict__ b1w,
    const float* __restrict__ BBb2, const int* __restrict__ Pib2,
    const float* __restrict__ GGb2, const float* __restrict__ ib2,
    float* __restrict__ b2w, const float* __restrict__ x,
    __hip_bfloat16* __restrict__ xb) {
  __shared__ __align__(16) float s[9216];
  __shared__ float red[4];
  int b = blockIdx.x, t = threadIdx.x;

  if (b >= 98) {
    int job = b - 98;
    int pipe = job >> 9, chunk = job & 511;
    const float* BB = pipe ? BB2 : BB1;
    const int* Pi = pipe ? Pi2 : Pi1;
    const float* GG = pipe ? GG2 : GG1;

    // ---- phase 0: issue ALL streaming HBM loads first (64B/lane) ----
    long base = (long)chunk * 8192;
    const int4* p4 = (const int4*)(Pi + base);
    const float4* g4 = (const float4*)(GG + base);
    int4 pp[8];
    float4 gg[8];
#pragma unroll
    for (int j = 0; j < 8; ++j) {
      pp[j] = p4[t + j * 256];
      gg[j] = g4[t + j * 256];
    }

    // ---- phase 1: in-block m2 = fwht2048(BB*theta) (hides load latency) ----
    {
      float w8[8];
#pragma unroll
      for (int j = 0; j < 8; ++j) {
        int i = t + 256 * j;
        w8[j] = BB[i] * theta[i];
      }
      fwht2048_block(w8, s + 2304, s, t);
    }

    // ---- phase 2: gather + scale with prefetched registers ----
    float v[32];
    float lsum = 0.f;
#pragma unroll
    for (int j = 0; j < 8; ++j) {  // i = t*4 + e + j*1024
      lsum += gg[j].x * gg[j].x + gg[j].y * gg[j].y + gg[j].z * gg[j].z +
              gg[j].w * gg[j].w;
      v[j * 4 + 0] = s[pp[j].x & 2047] * gg[j].x;
      v[j * 4 + 1] = s[pp[j].y & 2047] * gg[j].y;
      v[j * 4 + 2] = s[pp[j].z & 2047] * gg[j].z;
      v[j * 4 + 3] = s[pp[j].w & 2047] * gg[j].w;
    }
    for (int off = 32; off; off >>= 1) lsum += __shfl_down(lsum, off, 64);
    if ((t & 63) == 0) red[t >> 6] = lsum;

#pragma unroll
    for (int e = 0; e < 4; ++e) reg_fwht<8, 4>(v + e);  // bits 10..12

    __syncthreads();  // tab reads + red writes complete; s reusable
    if (t == 0)
      partial[pipe * 512 + chunk] = red[0] + red[1] + red[2] + red[3];

#pragma unroll
    for (int j = 0; j < 8; ++j) {
      int A = t * 4 + 4 * (t >> 3) + j * 1152;
      *(float4*)(s + A) =
          make_float4(v[j * 4], v[j * 4 + 1], v[j * 4 + 2], v[j * 4 + 3]);
    }
    __syncthreads();
    {  // bits 5..9
      int b0 = (t & 31) + (t >> 5) * 1024;
      float w[32];
#pragma unroll
      for (int j2 = 0; j2 < 32; ++j2) {
        int i = b0 + j2 * 32;
        w[j2] = s[i + 4 * (i >> 5)];
      }
      reg_fwht<32, 1>(w);
#pragma unroll
      for (int j2 = 0; j2 < 32; ++j2) {
        int i = b0 + j2 * 32;
        s[i + 4 * (i >> 5)] = w[j2];
      }
    }
    __syncthreads();
    // bits 0..4: thread owns c = t*32..t*32+31 (contiguous)
#pragma unroll
    for (int q = 0; q < 8; ++q) {
      float4 r = *(const float4*)(s + t * 36 + q * 4);
      v[q * 4 + 0] = r.x;
      v[q * 4 + 1] = r.y;
      v[q * 4 + 2] = r.z;
      v[q * 4 + 3] = r.w;
    }
    reg_fwht<32, 1>(v);
    // transposed write: col-groups 2t, 2t+1; 32B per group
    unsigned short* o = m4b + (long)pipe * LLW;
    long a0 = (long)(2 * t) * 8192 + (long)chunk * 16;
#pragma unroll
    for (int q = 0; q < 4; ++q) {
      u16x8 pk;
#pragma unroll
      for (int e = 0; e < 8; ++e) pk[e] = f2bf(v[q * 8 + e]);
      *(u16x8*)(o + a0 + (q >> 1) * 8192 + (q & 1) * 8) = pk;
    }
  } else if (b < 96) {
    // ---- x -> bf16 conversion (96 light blocks, finish fast) ----
    int id0 = b * 256 + t;
#pragma unroll
    for (int it = 0; it < 2; ++it) {
      int id = id0 + it * 24576;
      float4 xv = ((const float4*)x)[id];
      ushort4 o;
      o.x = f2bf(xv.x);
      o.y = f2bf(xv.y);
      o.z = f2bf(xv.z);
      o.w = f2bf(xv.w);
      ((ushort4*)xb)[id] = o;
    }
  } else if (b == 96) {
    // ---- bias1: LL=4096, K=2048, DD=3072 ----
    float* tabd = s + 6144;
    float w[8];
#pragma unroll
    for (int j = 0; j < 8; ++j) {
      int i = t + 256 * j;
      w[j] = BBb1[i] * theta[i];
    }
    fwht2048_block(w, s, tabd, t);

    float w16[16];
    float lsum = 0.f;
#pragma unroll
    for (int j = 0; j < 16; ++j) {
      int i = t + 256 * j;
      float g = GGb1[i];
      lsum += g * g;
      w16[j] = tabd[Pib1[i] & 2047] * g;
    }
    reg_fwht<16, 1>(w16);  // bits 8..11
#pragma unroll
    for (int j = 0; j < 16; ++j) {
      int i = t + 256 * j;
      s[i + 4 * (i >> 5)] = w16[j];
    }
    for (int off = 32; off; off >>= 1) lsum += __shfl_down(lsum, off, 64);
    if ((t & 63) == 0) s[4608 + (t >> 6)] = lsum;
    __syncthreads();
    float S = s[4608] + s[4609] + s[4610] + s[4611];
    {  // bits 0..3
      int base16 = 16 * t + 4 * (t >> 1);
      float u[16];
#pragma unroll
      for (int q = 0; q < 4; ++q) {
        float4 r = *(float4*)(s + base16 + q * 4);
        u[q * 4 + 0] = r.x;
        u[q * 4 + 1] = r.y;
        u[q * 4 + 2] = r.z;
        u[q * 4 + 3] = r.w;
      }
      reg_fwht<16, 1>(u);
#pragma unroll
      for (int q = 0; q < 4; ++q)
        *(float4*)(s + base16 + q * 4) =
            make_float4(u[q * 4], u[q * 4 + 1], u[q * 4 + 2], u[q * 4 + 3]);
    }
    __syncthreads();
    {  // bits 4..7 + epilogue
      float scale = 1.0f / sqrtf(S * 3072.0f);
      int b0 = (t & 15) + 256 * (t >> 4);
      float u[16];
#pragma unroll
      for (int j = 0; j < 16; ++j) {
        int i = b0 + 16 * j;
        u[j] = s[i + 4 * (i >> 5)];
      }
      reg_fwht<16, 1>(u);
#pragma unroll
      for (int j = 0; j < 16; ++j) {
        int i = b0 + 16 * j;
        if (i < 3072) b1w[i] = ib1[i] + u[j] * scale;
      }
    }
  } else {
    // ---- bias2: LL=1024, K=1024, DD=768 ----
    float* tab2 = s;
    float* m42 = s + 1024;
    for (int i = t; i < 1024; i += 256) tab2[i] = BBb2[i] * theta[i];
    lds_fwht(tab2, 1024, t, 256);
    float lsum = 0.f;
    for (int i = t; i < 1024; i += 256) {
      float g = GGb2[i];
      lsum += g * g;
      m42[i] = tab2[Pib2[i] & 1023] * g;
    }
    for (int off = 32; off; off >>= 1) lsum += __shfl_down(lsum, off, 64);
    if ((t & 63) == 0) s[2048 + (t >> 6)] = lsum;
    lds_fwht(m42, 1024, t, 256);
    float S = s[2048] + s[2049] + s[2050] + s[2051];
    float scale = 1.0f / sqrtf(S * 768.0f);
    for (int i = t; i < 768; i += 256) b2w[i] = ib2[i] + m42[i] * scale;
  }
}

// ---------------- k_f2c: FWHT over bits 13..21 + epilogue, both pipes -------
// initW epilogue operand PREFETCHED at kernel start (18.9 MB HBM read
// overlaps the whole FWHT phase). Verified padded layout:
// idx(r,c) = r*20 + (r>>5)*16 + c (max 10475).
__global__ __launch_bounds__(256) void k_f2c(
    const unsigned short* __restrict__ m4b, const float* __restrict__ iW1,
    const float* __restrict__ iW2, const float* __restrict__ partial,
    __hip_bfloat16* __restrict__ W1b, __hip_bfloat16* __restrict__ W2b) {
  __shared__ __align__(16) float s[10480];
  __shared__ float red[4];
  int b = blockIdx.x, t = threadIdx.x;
  int pipe = b >> 9;
  int lb = b & 511;
  int g = ((lb & 7) << 6) | (lb >> 3);
  int l0 = g * 16;
  const unsigned short* mp = m4b + (long)pipe * LLW + (long)g * 8192;
  const float* initW = pipe ? iW2 : iW1;
  unsigned short* outW = (unsigned short*)(pipe ? W2b : W1b);

  // ---- prefetch initW for the epilogue (issued before all LDS work) ----
  float4 ivp[5];
#pragma unroll
  for (int u = 0; u < 5; ++u) {
    int idx = t + u * 256;
    if (idx < 1152) {
      int r = idx >> 2, c4 = (idx & 3) * 4;
      ivp[u] = *(const float4*)(initW + (long)r * 8192 + l0 + c4);
    }
  }

  // reduce the 512 per-block sum(GG^2) partials (L2-hot) -> red[]
  {
    float ps = partial[pipe * 512 + t] + partial[pipe * 512 + 256 + t];
    for (int off = 32; off; off >>= 1) ps += __shfl_down(ps, off, 64);
    if ((t & 63) == 0) red[t >> 6] = ps;
  }

  // contiguous 16KB read: elem idx = r*16 + cl
#pragma unroll
  for (int q = 0; q < 4; ++q) {
    u16x8 raw = *(const u16x8*)(mp + t * 32 + q * 8);
    int r = 2 * t + (q >> 1), cb = (q & 1) * 8;
    float* dp = s + r * 20 + (r >> 5) * 16 + cb;
    float4 f0, f1v;
    f0.x = __uint_as_float((unsigned)raw[0] << 16);
    f0.y = __uint_as_float((unsigned)raw[1] << 16);
    f0.z = __uint_as_float((unsigned)raw[2] << 16);
    f0.w = __uint_as_float((unsigned)raw[3] << 16);
    f1v.x = __uint_as_float((unsigned)raw[4] << 16);
    f1v.y = __uint_as_float((unsigned)raw[5] << 16);
    f1v.z = __uint_as_float((unsigned)raw[6] << 16);
    f1v.w = __uint_as_float((unsigned)raw[7] << 16);
    *(float4*)dp = f0;
    *(float4*)(dp + 4) = f1v;
  }
  __syncthreads();

  {  // row bits 0..4
    int c = t & 15, rg = t >> 4;
    float w[32];
#pragma unroll
    for (int j = 0; j < 32; ++j) {
      int r = rg * 32 + j;
      w[j] = s[r * 20 + (r >> 5) * 16 + c];
    }
    reg_fwht<32, 1>(w);
#pragma unroll
    for (int j = 0; j < 32; ++j) {
      int r = rg * 32 + j;
      s[r * 20 + (r >> 5) * 16 + c] = w[j];
    }
  }
  __syncthreads();

  {  // row bits 5..8
    int c = t & 15;
    float w[32];
#pragma unroll
    for (int k = 0; k < 2; ++k) {
      int b0 = (t >> 4) * 2 + k;
#pragma unroll
      for (int j4 = 0; j4 < 16; ++j4) {
        int r = b0 + 32 * j4;
        w[k * 16 + j4] = s[r * 20 + (r >> 5) * 16 + c];
      }
      reg_fwht<16, 1>(w + k * 16);
#pragma unroll
      for (int j4 = 0; j4 < 16; ++j4) {
        int r = b0 + 32 * j4;
        s[r * 20 + (r >> 5) * 16 + c] = w[k * 16 + j4];
      }
    }
  }
  __syncthreads();

  float S = red[0] + red[1] + red[2] + red[3];
  float scale = 1.0f / sqrtf(S * 2359296.0f);
#pragma unroll
  for (int u = 0; u < 5; ++u) {  // 288 rows * 4 f4-chunks = 1152
    int idx = t + u * 256;
    if (idx < 1152) {
      int r = idx >> 2, c4 = (idx & 3) * 4;
      const float* sp = s + r * 20 + (r >> 5) * 16 + c4;
      long gi = (long)r * 8192 + l0 + c4;
      ushort4 pk;
      pk.x = f2bf(ivp[u].x + sp[0] * scale);
      pk.y = f2bf(ivp[u].y + sp[1] * scale);
      pk.z = f2bf(ivp[u].z + sp[2] * scale);
      pk.w = f2bf(ivp[u].w + sp[3] * scale);
      *(ushort4*)(outW + gi) = pk;
    }
  }
}

// ---------------- MFMA GEMM, in-block split-K + LDS reduce ------------------
// grid must be exactly (M/16)*(N/16/NACC)*SPLITK/4 blocks of 256 threads.
template <int NACC, int SPLITK, bool RELU, bool OUT_BF16>
__global__ __launch_bounds__(256) void k_gemm(
    const __hip_bfloat16* __restrict__ A, const __hip_bfloat16* __restrict__ B,
    const float* __restrict__ bias, void* __restrict__ C, int M, int N, int K) {
  __shared__ float red[4 * NACC * 320];  // [wave][acc][lane*5+r], pad 5
  int wave = threadIdx.x >> 6, lane = threadIdx.x & 63;
  int tileid = blockIdx.x * (4 / SPLITK) + wave / SPLITK;
  int sk = wave % SPLITK;
  int ntiles = N / (16 * NACC);
  int mt = tileid / ntiles, nt = tileid % ntiles;
  int ml = lane & 15;
  int q = lane >> 4;
  const short* As = (const short*)A;
  const short* Bs = (const short*)B;
  long arow = (long)(mt * 16 + ml) * K + q * 8;
  int KS = K / SPLITK, k0 = sk * KS;
  f32x4 acc[NACC] = {};
  for (int k = k0; k < k0 + KS; k += 32) {
    bf16x8 av = *(const bf16x8*)(As + arow + k);
#pragma unroll
    for (int a = 0; a < NACC; ++a) {
      int n = nt * 16 * NACC + a * 16 + ml;
      bf16x8 bv = *(const bf16x8*)(Bs + (long)n * K + q * 8 + k);
      acc[a] = __builtin_amdgcn_mfma_f32_16x16x32_bf16(av, bv, acc[a], 0, 0, 0);
    }
  }
#pragma unroll
  for (int a = 0; a < NACC; ++a)
#pragma unroll
    for (int r = 0; r < 4; ++r)
      red[(wave * NACC + a) * 320 + lane * 5 + r] = acc[a][r];
  __syncthreads();
  if (sk == 0) {
#pragma unroll
    for (int a = 0; a < NACC; ++a) {
      int n = nt * 16 * NACC + a * 16 + ml;
      float bv = bias[n];
#pragma unroll
      for (int r = 0; r < 4; ++r) {
        float vv = bv;
#pragma unroll
        for (int j = 0; j < SPLITK; ++j)
          vv += red[((wave + j) * NACC + a) * 320 + lane * 5 + r];
        int mm = mt * 16 + q * 4 + r;
        if (RELU) vv = fmaxf(vv, 0.f);
        if (OUT_BF16)
          ((__hip_bfloat16*)C)[(long)mm * N + n] = __float2bfloat16(vv);
        else
          ((float*)C)[(long)mm * N + n] = vv;
      }
    }
  }
}

// ---------------- workspace layout (bytes) ----------------------------------
#define OFF_PART 0                          // 1024 f32 partials
#define OFF_M2S 4096                        // (unused)
#define OFF_M4B (OFF_M2S + 16384)           // 2*LLW bf16 = 16 MiB
#define OFF_W1B (OFF_M4B + 2 * LLW * 2)     // 2359296 bf16
#define OFF_W2B (OFF_W1B + 4718592)
#define OFF_HB (OFF_W2B + 4718592)          // 256*3072 bf16
#define OFF_XB (OFF_HB + 1572864)           // 256*768 bf16
#define OFF_B1 (OFF_XB + 393216)            // 3072 f32
#define OFF_B2 (OFF_B1 + 12288)             // 768 f32

extern "C" void kernel_launch(void* const* d_in, const int* in_sizes, int n_in,
                              void* d_out, int out_size, void* d_ws,
                              size_t ws_size, hipStream_t stream) {
  const float* x = (const float*)d_in[0];
  const float* theta = (const float*)d_in[1];
  const float* iW1 = (const float*)d_in[2];
  const float* ib1 = (const float*)d_in[3];
  const float* iW2 = (const float*)d_in[4];
  const float* ib2 = (const float*)d_in[5];
  const float* BB_W1 = (const float*)d_in[6];
  const int* Pi_W1 = (const int*)d_in[7];
  const float* GG_W1 = (const float*)d_in[8];
  const float* BB_b1 = (const float*)d_in[9];
  const int* Pi_b1 = (const int*)d_in[10];
  const float* GG_b1 = (const float*)d_in[11];
  const float* BB_W2 = (const float*)d_in[12];
  const int* Pi_W2 = (const int*)d_in[13];
  const float* GG_W2 = (const float*)d_in[14];
  const float* BB_b2 = (const float*)d_in[15];
  const int* Pi_b2 = (const int*)d_in[16];
  const float* GG_b2 = (const float*)d_in[17];

  char* ws = (char*)d_ws;
  float* partial = (float*)(ws + OFF_PART);
  unsigned short* m4b = (unsigned short*)(ws + OFF_M4B);
  __hip_bfloat16* W1b = (__hip_bfloat16*)(ws + OFF_W1B);
  __hip_bfloat16* W2b = (__hip_bfloat16*)(ws + OFF_W2B);
  __hip_bfloat16* hb = (__hip_bfloat16*)(ws + OFF_HB);
  __hip_bfloat16* xb = (__hip_bfloat16*)(ws + OFF_XB);
  float* b1w = (float*)(ws + OFF_B1);
  float* b2w = (float*)(ws + OFF_B2);

  // 1: all front work (xb light blocks first, biases, 1024 prefetched pipes)
  k_front<<<1122, 256, 0, stream>>>(BB_W1, Pi_W1, GG_W1, BB_W2, Pi_W2, GG_W2,
                                    m4b, partial, theta, BB_b1, Pi_b1, GG_b1,
                                    ib1, b1w, BB_b2, Pi_b2, GG_b2, ib2, b2w, x,
                                    xb);
  // 2: W1b + W2b (both pipes, initW prefetched)
  k_f2c<<<1024, 256, 0, stream>>>(m4b, iW1, iW2, partial, W1b, W2b);
  // 3: h = relu(x @ W1^T + b1): 16*96 tiles, SPLITK=2 -> 768 blocks
  k_gemm<2, 2, true, true><<<768, 256, 0, stream>>>(xb, W1b, b1w, hb, 256,
                                                    3072, 768);
  // 4: out = h @ W2^T + b2: 16*48 tiles, SPLITK=4 -> 768 blocks
  k_gemm<1, 4, false, false><<<768, 256, 0, stream>>>(hb, W2b, b2w, d_out, 256,
                                                      768, 3072);
}

// Round 10
// 212.982 us; speedup vs baseline: 2.0698x; 1.0110x over previous
//
#include <hip/hip_runtime.h>
#include <hip/hip_bf16.h>

typedef __attribute__((ext_vector_type(8))) short bf16x8;
typedef __attribute__((ext_vector_type(8))) unsigned short u16x8;
typedef __attribute__((ext_vector_type(4))) float f32x4;

#define LLW 4194304

// ---------------- in-register FWHT over N entries spaced S apart ------------
template <int N, int S>
__device__ __forceinline__ void reg_fwht(float* v) {
#pragma unroll
  for (int h = 1; h < N; h <<= 1)
#pragma unroll
    for (int g = 0; g < N; g += 2 * h)
#pragma unroll
      for (int j = 0; j < h; ++j) {
        float a = v[(g + j) * S], b = v[(g + j + h) * S];
        v[(g + j) * S] = a + b;
        v[(g + j + h) * S] = a - b;
      }
}

__device__ __forceinline__ unsigned short f2bf(float f) {
  unsigned u = __float_as_uint(f);
  unsigned r = (u + 0x7fff + ((u >> 16) & 1)) >> 16;
  return (unsigned short)r;
}

// generic barriered LDS FWHT (tiny bias2 only; works for any T)
__device__ __forceinline__ void lds_fwht(float* s, int n, int tid, int T) {
  for (int h = 1; h < n; h <<= 1) {
    __syncthreads();
    for (int t = tid; t < (n >> 1); t += T) {
      int i0 = ((t & ~(h - 1)) << 1) | (t & (h - 1));
      int i1 = i0 + h;
      float a = s[i0], b = s[i1];
      s[i0] = a + b;
      s[i1] = a - b;
    }
  }
  __syncthreads();
}

// ---------------- register FWHT-2048, 256 workers, 512-thread-safe ----------
// act = (t < 256). All barriers executed by every thread in the block.
__device__ __forceinline__ void fwht2048_block_g(float w[8], float* pad,
                                                 float* dst, int t, bool act) {
  if (act) {
    reg_fwht<8, 1>(w);  // bits 8..10
#pragma unroll
    for (int j = 0; j < 8; ++j) {
      int i = t + 256 * j;
      pad[i + 4 * (i >> 5)] = w[j];
    }
  }
  __syncthreads();
  if (act) {  // bits 0..2
    int base = 8 * t + 4 * (t >> 2);
    float4 a = *(float4*)(pad + base);
    float4 b = *(float4*)(pad + base + 4);
    float u[8] = {a.x, a.y, a.z, a.w, b.x, b.y, b.z, b.w};
    reg_fwht<8, 1>(u);
    *(float4*)(pad + base) = make_float4(u[0], u[1], u[2], u[3]);
    *(float4*)(pad + base + 4) = make_float4(u[4], u[5], u[6], u[7]);
  }
  __syncthreads();
  if (act) {  // bits 3..5
    int b0 = (t & 7) + 64 * (t >> 3);
    float u[8];
#pragma unroll
    for (int j = 0; j < 8; ++j) {
      int i = b0 + 8 * j;
      u[j] = pad[i + 4 * (i >> 5)];
    }
    reg_fwht<8, 1>(u);
#pragma unroll
    for (int j = 0; j < 8; ++j) {
      int i = b0 + 8 * j;
      pad[i + 4 * (i >> 5)] = u[j];
    }
  }
  __syncthreads();
  if (act) {  // bits 6..7 -> dst unpadded
#pragma unroll
    for (int g = 0; g < 2; ++g) {
      int b0 = (t & 63) + 256 * ((g << 2) | (t >> 6));
      float u[4];
#pragma unroll
      for (int j = 0; j < 4; ++j) {
        int i = b0 + 64 * j;
        u[j] = pad[i + 4 * (i >> 5)];
      }
      reg_fwht<4, 1>(u);
#pragma unroll
      for (int j = 0; j < 4; ++j) dst[b0 + 64 * j] = u[j];
    }
  }
  __syncthreads();
}

// ---------------- k_front: 512 threads/block for FULL 32-wave occupancy -----
// xb 0..95, bias1=96, bias2=97, pipes 98..1121. LDS 36.9KB -> 4 blk/CU;
// 512 thr/blk -> 4x8 = 32 waves/CU (vs 16 at 256 thr) -> 2x latency hiding.
// Pipe: prefetch all Pi/GG into VGPRs, m2 in-block (hides latency), then
// FWHT-8192 as: in-reg bits 11..12, LDS rounds bits 7..10 / 3..6, final
// in-reg bits 0..2 + bf16 pack to m4b TRANSPOSED by 16-col groups:
// elem (chunk r, pos c) at (c>>4)*8192 + r*16 + (c&15).
__global__ __launch_bounds__(512, 6) void k_front(
    const float* __restrict__ BB1, const int* __restrict__ Pi1,
    const float* __restrict__ GG1, const float* __restrict__ BB2,
    const int* __restrict__ Pi2, const float* __restrict__ GG2,
    unsigned short* __restrict__ m4b, float* __restrict__ partial,
    const float* __restrict__ theta, const float* __restrict__ BBb1,
    const int* __restrict__ Pib1, const float* __restrict__ GGb1,
    const float* __restrict__ ib1, float* __restrict__ b1w,
    const float* __restrict__ BBb2, const int* __restrict__ Pib2,
    const float* __restrict__ GGb2, const float* __restrict__ ib2,
    float* __restrict__ b2w, const float* __restrict__ x,
    __hip_bfloat16* __restrict__ xb) {
  __shared__ __align__(16) float s[9216];
  __shared__ float red[8];
  int b = blockIdx.x, t = threadIdx.x;

  if (b >= 98) {
    int job = b - 98;
    int pipe = job >> 9, chunk = job & 511;
    const float* BB = pipe ? BB2 : BB1;
    const int* Pi = pipe ? Pi2 : Pi1;
    const float* GG = pipe ? GG2 : GG1;

    // ---- phase 0: issue ALL streaming HBM loads (32B Pi + 32B GG /lane) ----
    long base = (long)chunk * 8192;
    const int4* p4 = (const int4*)(Pi + base);
    const float4* g4 = (const float4*)(GG + base);
    int4 pp[4];
    float4 gg[4];
#pragma unroll
    for (int j = 0; j < 4; ++j) {
      pp[j] = p4[t + j * 512];
      gg[j] = g4[t + j * 512];
    }

    // ---- phase 1: m2 = fwht2048(BB*theta), workers t<256 (hiding window) --
    {
      bool act = t < 256;
      float w8[8];
      if (act) {
#pragma unroll
        for (int j = 0; j < 8; ++j) {
          int i = t + 256 * j;
          w8[j] = BB[i] * theta[i];
        }
      }
      fwht2048_block_g(w8, s + 2304, s, t, act);
    }

    // ---- phase 2: gather + scale; elem i = 4*(t+512j)+e -> v[j*4+e] -------
    float v[16];
    float lsum = 0.f;
#pragma unroll
    for (int j = 0; j < 4; ++j) {
      lsum += gg[j].x * gg[j].x + gg[j].y * gg[j].y + gg[j].z * gg[j].z +
              gg[j].w * gg[j].w;
      v[j * 4 + 0] = s[pp[j].x & 2047] * gg[j].x;
      v[j * 4 + 1] = s[pp[j].y & 2047] * gg[j].y;
      v[j * 4 + 2] = s[pp[j].z & 2047] * gg[j].z;
      v[j * 4 + 3] = s[pp[j].w & 2047] * gg[j].w;
    }
    for (int off = 32; off; off >>= 1) lsum += __shfl_down(lsum, off, 64);
    if ((t & 63) == 0) red[t >> 6] = lsum;

    // bits 11..12 in-reg (j dimension)
#pragma unroll
    for (int e = 0; e < 4; ++e) reg_fwht<4, 4>(v + e);

    __syncthreads();  // m2 reads done, red[] written; s reusable
    if (t == 0) {
      float S = 0.f;
#pragma unroll
      for (int i = 0; i < 8; ++i) S += red[i];
      partial[pipe * 512 + chunk] = S;
    }

    // store v: float4 at i0 = 4t + 2048j; padded addr = i0 + 4*(i0>>5)
#pragma unroll
    for (int j = 0; j < 4; ++j) {
      int A = 4 * t + 4 * (t >> 3) + 2304 * j;
      *(float4*)(s + A) =
          make_float4(v[j * 4], v[j * 4 + 1], v[j * 4 + 2], v[j * 4 + 3]);
    }
    __syncthreads();
    {  // round B: bits 7..10; i = low7 + 128k + 2048*hi2
      int low7 = t & 127, hi2 = t >> 7;
      float w[16];
#pragma unroll
      for (int k = 0; k < 16; ++k) {
        int i = low7 + 128 * k + 2048 * hi2;
        w[k] = s[i + 4 * (i >> 5)];
      }
      reg_fwht<16, 1>(w);
#pragma unroll
      for (int k = 0; k < 16; ++k) {
        int i = low7 + 128 * k + 2048 * hi2;
        s[i + 4 * (i >> 5)] = w[k];
      }
    }
    __syncthreads();
    {  // round C: bits 3..6; i = low3 + 8k + 128*hi6
      int low3 = t & 7, hi6 = t >> 3;
      float w[16];
#pragma unroll
      for (int k = 0; k < 16; ++k) {
        int i = low3 + 8 * k + 128 * hi6;
        w[k] = s[i + 4 * (i >> 5)];
      }
      reg_fwht<16, 1>(w);
#pragma unroll
      for (int k = 0; k < 16; ++k) {
        int i = low3 + 8 * k + 128 * hi6;
        s[i + 4 * (i >> 5)] = w[k];
      }
    }
    __syncthreads();
    // round D: bits 0..2 in-reg from contiguous 8; pack + transposed write
    unsigned short* o = m4b + (long)pipe * LLW;
#pragma unroll
    for (int g = 0; g < 2; ++g) {
      int hi10 = t + 512 * g;  // elem block: c = 8*hi10 + k
      int i0 = 8 * hi10;
      int A = i0 + 4 * (i0 >> 5);
      float4 a = *(const float4*)(s + A);
      float4 c4 = *(const float4*)(s + A + 4);
      float u[8] = {a.x, a.y, a.z, a.w, c4.x, c4.y, c4.z, c4.w};
      reg_fwht<8, 1>(u);
      u16x8 pk;
#pragma unroll
      for (int e = 0; e < 8; ++e) pk[e] = f2bf(u[e]);
      long addr = (long)(hi10 >> 1) * 8192 + (long)chunk * 16 + (hi10 & 1) * 8;
      *(u16x8*)(o + addr) = pk;
    }
  } else if (b < 96) {
    // ---- x -> bf16 conversion (96 light blocks, 1 float4/thread) ----
    int id = b * 512 + t;
    float4 xv = ((const float4*)x)[id];
    ushort4 ov;
    ov.x = f2bf(xv.x);
    ov.y = f2bf(xv.y);
    ov.z = f2bf(xv.z);
    ov.w = f2bf(xv.w);
    ((ushort4*)xb)[id] = ov;
  } else if (b == 96) {
    // ---- bias1: LL=4096, K=2048, DD=3072 (workers t<256) ----
    bool act = t < 256;
    float* tabd = s + 6144;
    float w[8];
    if (act) {
#pragma unroll
      for (int j = 0; j < 8; ++j) {
        int i = t + 256 * j;
        w[j] = BBb1[i] * theta[i];
      }
    }
    fwht2048_block_g(w, s, tabd, t, act);

    float w16[16];
    float lsum = 0.f;
    if (act) {
#pragma unroll
      for (int j = 0; j < 16; ++j) {
        int i = t + 256 * j;
        float g = GGb1[i];
        lsum += g * g;
        w16[j] = tabd[Pib1[i] & 2047] * g;
      }
      reg_fwht<16, 1>(w16);  // bits 8..11
#pragma unroll
      for (int j = 0; j < 16; ++j) {
        int i = t + 256 * j;
        s[i + 4 * (i >> 5)] = w16[j];
      }
      for (int off = 32; off; off >>= 1) lsum += __shfl_down(lsum, off, 64);
      if ((t & 63) == 0) s[4608 + (t >> 6)] = lsum;
    }
    __syncthreads();
    float S = s[4608] + s[4609] + s[4610] + s[4611];
    if (act) {  // bits 0..3
      int base16 = 16 * t + 4 * (t >> 1);
      float u[16];
#pragma unroll
      for (int q = 0; q < 4; ++q) {
        float4 r = *(float4*)(s + base16 + q * 4);
        u[q * 4 + 0] = r.x;
        u[q * 4 + 1] = r.y;
        u[q * 4 + 2] = r.z;
        u[q * 4 + 3] = r.w;
      }
      reg_fwht<16, 1>(u);
#pragma unroll
      for (int q = 0; q < 4; ++q)
        *(float4*)(s + base16 + q * 4) =
            make_float4(u[q * 4], u[q * 4 + 1], u[q * 4 + 2], u[q * 4 + 3]);
    }
    __syncthreads();
    if (act) {  // bits 4..7 + epilogue
      float scale = 1.0f / sqrtf(S * 3072.0f);
      int b0 = (t & 15) + 256 * (t >> 4);
      float u[16];
#pragma unroll
      for (int j = 0; j < 16; ++j) {
        int i = b0 + 16 * j;
        u[j] = s[i + 4 * (i >> 5)];
      }
      reg_fwht<16, 1>(u);
#pragma unroll
      for (int j = 0; j < 16; ++j) {
        int i = b0 + 16 * j;
        if (i < 3072) b1w[i] = ib1[i] + u[j] * scale;
      }
    }
  } else {
    // ---- bias2: LL=1024, K=1024, DD=768 (all 512 threads) ----
    float* tab2 = s;
    float* m42 = s + 1024;
    for (int i = t; i < 1024; i += 512) tab2[i] = BBb2[i] * theta[i];
    lds_fwht(tab2, 1024, t, 512);
    float lsum = 0.f;
    for (int i = t; i < 1024; i += 512) {
      float g = GGb2[i];
      lsum += g * g;
      m42[i] = tab2[Pib2[i] & 1023] * g;
    }
    for (int off = 32; off; off >>= 1) lsum += __shfl_down(lsum, off, 64);
    if ((t & 63) == 0) s[2048 + (t >> 6)] = lsum;
    lds_fwht(m42, 1024, t, 512);
    float S = 0.f;
#pragma unroll
    for (int i = 0; i < 8; ++i) S += s[2048 + i];
    float scale = 1.0f / sqrtf(S * 768.0f);
    for (int i = t; i < 768; i += 512) b2w[i] = ib2[i] + m42[i] * scale;
  }
}

// ---------------- k_f2c: FWHT over bits 13..21 + epilogue, both pipes -------
// initW epilogue operand PREFETCHED at kernel start (overlaps FWHT phase).
// Verified padded layout: idx(r,c) = r*20 + (r>>5)*16 + c (max 10475).
__global__ __launch_bounds__(256) void k_f2c(
    const unsigned short* __restrict__ m4b, const float* __restrict__ iW1,
    const float* __restrict__ iW2, const float* __restrict__ partial,
    __hip_bfloat16* __restrict__ W1b, __hip_bfloat16* __restrict__ W2b) {
  __shared__ __align__(16) float s[10480];
  __shared__ float red[4];
  int b = blockIdx.x, t = threadIdx.x;
  int pipe = b >> 9;
  int lb = b & 511;
  int g = ((lb & 7) << 6) | (lb >> 3);
  int l0 = g * 16;
  const unsigned short* mp = m4b + (long)pipe * LLW + (long)g * 8192;
  const float* initW = pipe ? iW2 : iW1;
  unsigned short* outW = (unsigned short*)(pipe ? W2b : W1b);

  // ---- prefetch initW for the epilogue (issued before all LDS work) ----
  float4 ivp[5];
#pragma unroll
  for (int u = 0; u < 5; ++u) {
    int idx = t + u * 256;
    if (idx < 1152) {
      int r = idx >> 2, c4 = (idx & 3) * 4;
      ivp[u] = *(const float4*)(initW + (long)r * 8192 + l0 + c4);
    }
  }

  // reduce the 512 per-block sum(GG^2) partials (L2-hot) -> red[]
  {
    float ps = partial[pipe * 512 + t] + partial[pipe * 512 + 256 + t];
    for (int off = 32; off; off >>= 1) ps += __shfl_down(ps, off, 64);
    if ((t & 63) == 0) red[t >> 6] = ps;
  }

  // contiguous 16KB read: elem idx = r*16 + cl
#pragma unroll
  for (int q = 0; q < 4; ++q) {
    u16x8 raw = *(const u16x8*)(mp + t * 32 + q * 8);
    int r = 2 * t + (q >> 1), cb = (q & 1) * 8;
    float* dp = s + r * 20 + (r >> 5) * 16 + cb;
    float4 f0, f1v;
    f0.x = __uint_as_float((unsigned)raw[0] << 16);
    f0.y = __uint_as_float((unsigned)raw[1] << 16);
    f0.z = __uint_as_float((unsigned)raw[2] << 16);
    f0.w = __uint_as_float((unsigned)raw[3] << 16);
    f1v.x = __uint_as_float((unsigned)raw[4] << 16);
    f1v.y = __uint_as_float((unsigned)raw[5] << 16);
    f1v.z = __uint_as_float((unsigned)raw[6] << 16);
    f1v.w = __uint_as_float((unsigned)raw[7] << 16);
    *(float4*)dp = f0;
    *(float4*)(dp + 4) = f1v;
  }
  __syncthreads();

  {  // row bits 0..4
    int c = t & 15, rg = t >> 4;
    float w[32];
#pragma unroll
    for (int j = 0; j < 32; ++j) {
      int r = rg * 32 + j;
      w[j] = s[r * 20 + (r >> 5) * 16 + c];
    }
    reg_fwht<32, 1>(w);
#pragma unroll
    for (int j = 0; j < 32; ++j) {
      int r = rg * 32 + j;
      s[r * 20 + (r >> 5) * 16 + c] = w[j];
    }
  }
  __syncthreads();

  {  // row bits 5..8
    int c = t & 15;
    float w[32];
#pragma unroll
    for (int k = 0; k < 2; ++k) {
      int b0 = (t >> 4) * 2 + k;
#pragma unroll
      for (int j4 = 0; j4 < 16; ++j4) {
        int r = b0 + 32 * j4;
        w[k * 16 + j4] = s[r * 20 + (r >> 5) * 16 + c];
      }
      reg_fwht<16, 1>(w + k * 16);
#pragma unroll
      for (int j4 = 0; j4 < 16; ++j4) {
        int r = b0 + 32 * j4;
        s[r * 20 + (r >> 5) * 16 + c] = w[k * 16 + j4];
      }
    }
  }
  __syncthreads();

  float S = red[0] + red[1] + red[2] + red[3];
  float scale = 1.0f / sqrtf(S * 2359296.0f);
#pragma unroll
  for (int u = 0; u < 5; ++u) {  // 288 rows * 4 f4-chunks = 1152
    int idx = t + u * 256;
    if (idx < 1152) {
      int r = idx >> 2, c4 = (idx & 3) * 4;
      const float* sp = s + r * 20 + (r >> 5) * 16 + c4;
      long gi = (long)r * 8192 + l0 + c4;
      ushort4 pk;
      pk.x = f2bf(ivp[u].x + sp[0] * scale);
      pk.y = f2bf(ivp[u].y + sp[1] * scale);
      pk.z = f2bf(ivp[u].z + sp[2] * scale);
      pk.w = f2bf(ivp[u].w + sp[3] * scale);
      *(ushort4*)(outW + gi) = pk;
    }
  }
}

// ---------------- MFMA GEMM, in-block split-K + LDS reduce ------------------
// grid must be exactly (M/16)*(N/16/NACC)*SPLITK/4 blocks of 256 threads.
template <int NACC, int SPLITK, bool RELU, bool OUT_BF16>
__global__ __launch_bounds__(256) void k_gemm(
    const __hip_bfloat16* __restrict__ A, const __hip_bfloat16* __restrict__ B,
    const float* __restrict__ bias, void* __restrict__ C, int M, int N, int K) {
  __shared__ float red[4 * NACC * 320];  // [wave][acc][lane*5+r], pad 5
  int wave = threadIdx.x >> 6, lane = threadIdx.x & 63;
  int tileid = blockIdx.x * (4 / SPLITK) + wave / SPLITK;
  int sk = wave % SPLITK;
  int ntiles = N / (16 * NACC);
  int mt = tileid / ntiles, nt = tileid % ntiles;
  int ml = lane & 15;
  int q = lane >> 4;
  const short* As = (const short*)A;
  const short* Bs = (const short*)B;
  long arow = (long)(mt * 16 + ml) * K + q * 8;
  int KS = K / SPLITK, k0 = sk * KS;
  f32x4 acc[NACC] = {};
  for (int k = k0; k < k0 + KS; k += 32) {
    bf16x8 av = *(const bf16x8*)(As + arow + k);
#pragma unroll
    for (int a = 0; a < NACC; ++a) {
      int n = nt * 16 * NACC + a * 16 + ml;
      bf16x8 bv = *(const bf16x8*)(Bs + (long)n * K + q * 8 + k);
      acc[a] = __builtin_amdgcn_mfma_f32_16x16x32_bf16(av, bv, acc[a], 0, 0, 0);
    }
  }
#pragma unroll
  for (int a = 0; a < NACC; ++a)
#pragma unroll
    for (int r = 0; r < 4; ++r)
      red[(wave * NACC + a) * 320 + lane * 5 + r] = acc[a][r];
  __syncthreads();
  if (sk == 0) {
#pragma unroll
    for (int a = 0; a < NACC; ++a) {
      int n = nt * 16 * NACC + a * 16 + ml;
      float bv = bias[n];
#pragma unroll
      for (int r = 0; r < 4; ++r) {
        float vv = bv;
#pragma unroll
        for (int j = 0; j < SPLITK; ++j)
          vv += red[((wave + j) * NACC + a) * 320 + lane * 5 + r];
        int mm = mt * 16 + q * 4 + r;
        if (RELU) vv = fmaxf(vv, 0.f);
        if (OUT_BF16)
          ((__hip_bfloat16*)C)[(long)mm * N + n] = __float2bfloat16(vv);
        else
          ((float*)C)[(long)mm * N + n] = vv;
      }
    }
  }
}

// ---------------- workspace layout (bytes) ----------------------------------
#define OFF_PART 0                          // 1024 f32 partials
#define OFF_M2S 4096                        // (unused)
#define OFF_M4B (OFF_M2S + 16384)           // 2*LLW bf16 = 16 MiB
#define OFF_W1B (OFF_M4B + 2 * LLW * 2)     // 2359296 bf16
#define OFF_W2B (OFF_W1B + 4718592)
#define OFF_HB (OFF_W2B + 4718592)          // 256*3072 bf16
#define OFF_XB (OFF_HB + 1572864)           // 256*768 bf16
#define OFF_B1 (OFF_XB + 393216)            // 3072 f32
#define OFF_B2 (OFF_B1 + 12288)             // 768 f32

extern "C" void kernel_launch(void* const* d_in, const int* in_sizes, int n_in,
                              void* d_out, int out_size, void* d_ws,
                              size_t ws_size, hipStream_t stream) {
  const float* x = (const float*)d_in[0];
  const float* theta = (const float*)d_in[1];
  const float* iW1 = (const float*)d_in[2];
  const float* ib1 = (const float*)d_in[3];
  const float* iW2 = (const float*)d_in[4];
  const float* ib2 = (const float*)d_in[5];
  const float* BB_W1 = (const float*)d_in[6];
  const int* Pi_W1 = (const int*)d_in[7];
  const float* GG_W1 = (const float*)d_in[8];
  const float* BB_b1 = (const float*)d_in[9];
  const int* Pi_b1 = (const int*)d_in[10];
  const float* GG_b1 = (const float*)d_in[11];
  const float* BB_W2 = (const float*)d_in[12];
  const int* Pi_W2 = (const int*)d_in[13];
  const float* GG_W2 = (const float*)d_in[14];
  const float* BB_b2 = (const float*)d_in[15];
  const int* Pi_b2 = (const int*)d_in[16];
  const float* GG_b2 = (const float*)d_in[17];

  char* ws = (char*)d_ws;
  float* partial = (float*)(ws + OFF_PART);
  unsigned short* m4b = (unsigned short*)(ws + OFF_M4B);
  __hip_bfloat16* W1b = (__hip_bfloat16*)(ws + OFF_W1B);
  __hip_bfloat16* W2b = (__hip_bfloat16*)(ws + OFF_W2B);
  __hip_bfloat16* hb = (__hip_bfloat16*)(ws + OFF_HB);
  __hip_bfloat16* xb = (__hip_bfloat16*)(ws + OFF_XB);
  float* b1w = (float*)(ws + OFF_B1);
  float* b2w = (float*)(ws + OFF_B2);

  // 1: all front work, 512-thread blocks (xb first, biases, 1024 pipes)
  k_front<<<1122, 512, 0, stream>>>(BB_W1, Pi_W1, GG_W1, BB_W2, Pi_W2, GG_W2,
                                    m4b, partial, theta, BB_b1, Pi_b1, GG_b1,
                                    ib1, b1w, BB_b2, Pi_b2, GG_b2, ib2, b2w, x,
                                    xb);
  // 2: W1b + W2b (both pipes, initW prefetched)
  k_f2c<<<1024, 256, 0, stream>>>(m4b, iW1, iW2, partial, W1b, W2b);
  // 3: h = relu(x @ W1^T + b1): 16*96 tiles, SPLITK=2 -> 768 blocks
  k_gemm<2, 2, true, true><<<768, 256, 0, stream>>>(xb, W1b, b1w, hb, 256,
                                                    3072, 768);
  // 4: out = h @ W2^T + b2: 16*48 tiles, SPLITK=4 -> 768 blocks
  k_gemm<1, 4, false, false><<<768, 256, 0, stream>>>(hb, W2b, b2w, d_out, 256,
                                                      768, 3072);
}